// Round 12
// baseline (320.718 us; speedup 1.0000x reference)
//
#include <hip/hip_runtime.h>
#include <cstdint>
#include <cstddef>

#define L_LAYERS 3
#define H_HEADS 8
#define D_EMB 128
#define DKV 16
#define FF_DIM 512
#define B_BATCH 32
#define N_SEQ 512
#define F_INP 16
#define OUT_DIM 3
#define M_ROWS (B_BATCH * N_SEQ)   // 16384

typedef unsigned short ushort_t;
typedef unsigned int uint_t;
typedef __attribute__((ext_vector_type(8))) short short8;
typedef __attribute__((ext_vector_type(4))) float f32x4;
typedef __attribute__((ext_vector_type(16))) float f32x16;

__device__ inline ushort_t f2bf(float x) {   // RNE float->bf16
    union { float f; uint_t u; } v; v.f = x;
    uint_t r = v.u + 0x7fffu + ((v.u >> 16) & 1u);
    return (ushort_t)(r >> 16);
}

__device__ inline uint_t pack2bf(float a, float b) {  // RNE pack: lo=a, hi=b
    union { float f; uint_t u; } ua, ub;
    ua.f = a; ub.f = b;
    uint_t ra = ua.u + 0x7fffu + ((ua.u >> 16) & 1u);
    uint_t rb = ub.u + 0x7fffu + ((ub.u >> 16) & 1u);
    return (ra >> 16) | (rb & 0xffff0000u);
}

__device__ inline void gload16(const void* g, void* l) {
    __builtin_amdgcn_global_load_lds(
        (const __attribute__((address_space(1))) unsigned int*)g,
        (__attribute__((address_space(3))) unsigned int*)l, 16, 0, 0);
}

// ---------------- fused preprocessing (+ pbsum zeroing) ----------------
#define PM_BLK 32768
#define RQ_BLK 576
#define TW_BLK 192
#define T1_BLK 768
#define T2_BLK 768
#define PB_BLK 16
#define EM_BLK 8192
__global__ __launch_bounds__(256) void preproc_kernel(
        const int* __restrict__ mask, unsigned long long* __restrict__ pm,
        const float* __restrict__ Wq, const float* __restrict__ Wk,
        const float* __restrict__ Wv, ushort_t* __restrict__ wqkvT,
        const float* __restrict__ Wout, ushort_t* __restrict__ woutT,
        const float* __restrict__ Wff1, ushort_t* __restrict__ wff1T,
        const float* __restrict__ Wff2, ushort_t* __restrict__ wff2T,
        float* __restrict__ pbsum,
        const float* __restrict__ x, const float* __restrict__ We,
        float* __restrict__ hf, ushort_t* __restrict__ hb) {
    int bx = blockIdx.x;
    const int tid = threadIdx.x;
    if (bx < PM_BLK) {
        int gid = bx * 256 + tid;
        int v = mask[gid];
        unsigned long long bal = __ballot(v != 0);
        if ((tid & 63) == 0) pm[gid >> 6] = bal;
        return;
    }
    bx -= PM_BLK;
    if (bx < RQ_BLK) {
        int idx = bx * 256 + tid;
        int d = idx & 127;
        int n = (idx >> 7) % 384;
        int l = idx / (384 * 128);
        int proj = n >> 7, hh = (n & 127) >> 4, kk = n & 15;
        const float* src = proj == 0 ? Wq : proj == 1 ? Wk : Wv;
        wqkvT[idx] = f2bf(src[((size_t)(l * 8 + hh) * 128 + d) * 16 + kk]);
        return;
    }
    bx -= RQ_BLK;
    if (bx < TW_BLK + T1_BLK + T2_BLK) {
        const float* src; ushort_t* dst; int R, C;
        if (bx < TW_BLK) { src = Wout; dst = woutT; R = 128; C = 128; }
        else if (bx < TW_BLK + T1_BLK) { src = Wff1; dst = wff1T; R = 128; C = 512; bx -= TW_BLK; }
        else { src = Wff2; dst = wff2T; R = 512; C = 128; bx -= TW_BLK + T1_BLK; }
        int idx = bx * 256 + tid;
        int b = idx / (R * C);
        int rem = idx - b * (R * C);
        int r = rem / C, c = rem - r * C;
        dst[(size_t)b * R * C + (size_t)c * R + r] = f2bf(src[idx]);
        return;
    }
    bx -= TW_BLK + T1_BLK + T2_BLK;
    if (bx < PB_BLK) {
        pbsum[bx * 256 + tid] = 0.f;
        return;
    }
    bx -= PB_BLK;
    {
        const int d = tid & 127;
        const int m = bx * 2 + (tid >> 7);
        const float* xr = x + (size_t)m * 16;
        float acc = 0.f;
#pragma unroll
        for (int k = 0; k < 16; k++) acc += xr[k] * We[k * 128 + d];
        acc = fmaxf(acc, 0.f);
        hf[(size_t)m * 128 + d] = acc;
        hb[(size_t)m * 128 + d] = f2bf(acc);
    }
}

// ---------------- fused QKV-GEMM + flash attention (v3: W frags direct from global) ----------------
// Block = (b,h,half): 512 blocks x 512 thr (8 waves), LDS 59.6 KB -> 2 blocks/CU. ONE barrier.
__global__ __launch_bounds__(512, 2) void qkv_attn_kernel(
        const ushort_t* __restrict__ hb,    // [16384][128] bf16
        const ushort_t* __restrict__ WqkvT, // layer slice [384][128] bf16 B^T
        const uint_t* __restrict__ pm,      // packed mask
        ushort_t* __restrict__ Aout) {      // [16384][128] bf16
    __shared__ __align__(16) ushort_t sm[29824];   // 59.6 KB
    ushort_t* Qs  = sm;            // [256][16]
    ushort_t* KF  = sm + 4096;     // 16 tiles * 512
    ushort_t* Vt  = sm + 12288;    // [16][520]
    ushort_t* Ps  = sm + 20608;    // 8 x 32x36

    const int tid = threadIdx.x;
    const int w = tid >> 6, L = tid & 63;
    const int lr = L & 15, lq = L >> 4;
    const int lane31 = L & 31, lhalf = L >> 5;
    const int bx = blockIdx.x;
    const int b = bx >> 4, h = (bx >> 1) & 7, half = bx & 1;

    // ---- QKV GEMM: A and W fragments direct from global (L2/L1-hot), no barriers ----
    const ushort_t* Ab = hb + (size_t)b * 512 * 128;
    for (int mc = 0; mc < 4; mc++) {
        f32x4 acc[3];
#pragma unroll
        for (int j = 0; j < 3; j++) acc[j] = (f32x4){0.f, 0.f, 0.f, 0.f};
#pragma unroll
        for (int k0 = 0; k0 < 128; k0 += 32) {
            short8 af = *(const short8*)(Ab + (size_t)(mc * 128 + w * 16 + lr) * 128 + k0 + lq * 8);
#pragma unroll
            for (int j = 0; j < 3; j++) {
                short8 bf = *(const short8*)(WqkvT + (size_t)(j * 128 + h * 16 + lr) * 128 + k0 + lq * 8);
                acc[j] = __builtin_amdgcn_mfma_f32_16x16x32_bf16(af, bf, acc[j], 0, 0, 0);
            }
        }
        // epilogue: C layout col = j*16+lr, row = lq*4+r
        const int rbase = mc * 128 + w * 16 + lq * 4;
#pragma unroll
        for (int r = 0; r < 4; r++) {
            const int key = rbase + r;
            KF[(key >> 5) * 512 + ((lr >> 3) * 32 + (key & 31)) * 8 + (lr & 7)] = f2bf(acc[1][r]);
            Vt[lr * 520 + key] = f2bf(acc[2][r]);
        }
        if ((mc >> 1) == half) {
            const int qb = (mc & 1) * 128 + w * 16 + lq * 4;
#pragma unroll
            for (int r = 0; r < 4; r++)
                Qs[(qb + r) * 16 + lr] = f2bf(acc[0][r] * 0.25f);
        }
    }
    __syncthreads();

    // ---- phase 2: v4 attention; wave owns 32 queries ----
    const int q0g = half * 256 + w * 32;
    const short8 qf = *(const short8*)&Qs[(w * 32 + lane31) * 16 + lhalf * 8];
    const uint_t* pmr = pm + (size_t)(b * 512 + q0g + lane31) * 16;
    const uint4 mwa = *(const uint4*)(pmr);
    const uint4 mwb = *(const uint4*)(pmr + 4);
    const uint4 mwc = *(const uint4*)(pmr + 8);
    const uint4 mwd = *(const uint4*)(pmr + 12);
    const uint_t mw[16] = {mwa.x, mwa.y, mwa.z, mwa.w, mwb.x, mwb.y, mwb.z, mwb.w,
                           mwc.x, mwc.y, mwc.z, mwc.w, mwd.x, mwd.y, mwd.z, mwd.w};
    const f32x16 zero16 = (f32x16)(0.f);

    float mx = -1e30f;
#pragma unroll
    for (int t = 0; t < 16; t++) {
        short8 kf = *(const short8*)&KF[t * 512 + L * 8];
        f32x16 s = __builtin_amdgcn_mfma_f32_32x32x16_bf16(kf, qf, zero16, 0, 0, 0);
#pragma unroll
        for (int r = 0; r < 16; r++) mx = fmaxf(mx, s[r]);
    }
    mx = fmaxf(mx, __shfl_xor(mx, 32));

    float lsum = 0.f;
    f32x4 oacc0 = (f32x4){0.f, 0.f, 0.f, 0.f};
    f32x4 oacc1 = (f32x4){0.f, 0.f, 0.f, 0.f};
#pragma unroll
    for (int t = 0; t < 16; t++) {
        short8 kf = *(const short8*)&KF[t * 512 + L * 8];
        f32x16 s = __builtin_amdgcn_mfma_f32_32x32x16_bf16(kf, qf, zero16, 0, 0, 0);
        const uint_t word = mw[t];
#pragma unroll
        for (int r = 0; r < 16; r++) {
            const int keyl = (r & 3) + 8 * (r >> 2) + 4 * lhalf;
            const float e = __expf(s[r] - mx);
            const float pv = (word & (1u << keyl)) ? e : 0.f;
            s[r] = pv;
            lsum += pv;
        }
#pragma unroll
        for (int g = 0; g < 4; g++) {
            const uint_t lo = pack2bf(s[g * 4 + 0], s[g * 4 + 1]);
            const uint_t hi = pack2bf(s[g * 4 + 2], s[g * 4 + 3]);
            *(uint2*)&Ps[w * 1152 + lane31 * 36 + g * 8 + 4 * lhalf] = make_uint2(lo, hi);
        }
        short8 vb = *(const short8*)&Vt[lr * 520 + t * 32 + lq * 8];
        short8 pa0 = *(const short8*)&Ps[w * 1152 + lr * 36 + lq * 8];
        short8 pa1 = *(const short8*)&Ps[w * 1152 + (16 + lr) * 36 + lq * 8];
        oacc0 = __builtin_amdgcn_mfma_f32_16x16x32_bf16(pa0, vb, oacc0, 0, 0, 0);
        oacc1 = __builtin_amdgcn_mfma_f32_16x16x32_bf16(pa1, vb, oacc1, 0, 0, 0);
    }
    lsum += __shfl_xor(lsum, 32);

#pragma unroll
    for (int qa = 0; qa < 2; qa++) {
        const f32x4 oa = qa ? oacc1 : oacc0;
#pragma unroll
        for (int rr = 0; rr < 4; rr++) {
            const int qloc = qa * 16 + lq * 4 + rr;
            const float ls = __shfl(lsum, qloc, 64);
            Aout[(size_t)(b * 512 + q0g + qloc) * 128 + h * 16 + lr] = f2bf(oa[rr] / ls);
        }
    }
}

// ---------------- fused layer tail v3: zero staging, 2 barriers ----------------
// A-frags (a16) and B-frags (WoT/W1T/W2T) read directly from global (L2/L1-hot,
// identical across blocks -> broadcast). LDS holds only row-local C1b + T.
__global__ __launch_bounds__(256, 2) void tail_kernel(
        const ushort_t* __restrict__ A,     // a16 [16384][128]
        const ushort_t* __restrict__ WoT,   // [128 n][128 k]
        const ushort_t* __restrict__ W1T,   // [512 n][128 k]
        const ushort_t* __restrict__ W2T,   // [128 n][512 k]
        const float* __restrict__ b1,
        const float* __restrict__ b2,
        float* __restrict__ hf, ushort_t* __restrict__ hb,
        float* __restrict__ pbsum, int accum) {
    __shared__ __align__(16) ushort_t C1b[32 * 136];   // 8.7 KB
    __shared__ __align__(16) ushort_t T[32 * 520];     // 33.3 KB

    const int tid = threadIdx.x;
    const int w = tid >> 6, l = tid & 63;
    const int lr = l & 15, lq = l >> 4;
    const int m0 = blockIdx.x * 32;

    // phase A: C1 = a16 @ WoT^T + h   (frags direct from global)
    f32x4 c1a[2][2];
#pragma unroll
    for (int i = 0; i < 2; i++)
#pragma unroll
        for (int j = 0; j < 2; j++) c1a[i][j] = (f32x4){0.f, 0.f, 0.f, 0.f};
#pragma unroll
    for (int k0 = 0; k0 < 128; k0 += 32) {
        short8 af[2], bfr[2];
#pragma unroll
        for (int i = 0; i < 2; i++)
            af[i] = *(const short8*)(A + (size_t)(m0 + i * 16 + lr) * 128 + k0 + lq * 8);
#pragma unroll
        for (int j = 0; j < 2; j++)
            bfr[j] = *(const short8*)(WoT + (size_t)(w * 32 + j * 16 + lr) * 128 + k0 + lq * 8);
#pragma unroll
        for (int i = 0; i < 2; i++)
#pragma unroll
            for (int j = 0; j < 2; j++)
                c1a[i][j] = __builtin_amdgcn_mfma_f32_16x16x32_bf16(af[i], bfr[j], c1a[i][j], 0, 0, 0);
    }
    float c1[2][2][4];
#pragma unroll
    for (int i = 0; i < 2; i++)
#pragma unroll
        for (int r = 0; r < 4; r++) {
            const int row = i * 16 + lq * 4 + r;
#pragma unroll
            for (int j = 0; j < 2; j++) {
                const int n = w * 32 + j * 16 + lr;
                const float v = c1a[i][j][r] + hf[(size_t)(m0 + row) * 128 + n];
                c1[i][j][r] = v;
                C1b[row * 136 + n] = f2bf(v);
            }
        }
    __syncthreads();

    // phase B: T = relu(C1 @ W1T^T + b1)  (W frags direct)
    f32x4 ta[2][8];
#pragma unroll
    for (int i = 0; i < 2; i++)
#pragma unroll
        for (int j = 0; j < 8; j++) ta[i][j] = (f32x4){0.f, 0.f, 0.f, 0.f};
#pragma unroll
    for (int k0 = 0; k0 < 128; k0 += 32) {
        short8 af[2], bfr[8];
#pragma unroll
        for (int i = 0; i < 2; i++)
            af[i] = *(const short8*)&C1b[(i * 16 + lr) * 136 + k0 + lq * 8];
#pragma unroll
        for (int j = 0; j < 8; j++)
            bfr[j] = *(const short8*)(W1T + (size_t)(w * 128 + j * 16 + lr) * 128 + k0 + lq * 8);
#pragma unroll
        for (int i = 0; i < 2; i++)
#pragma unroll
            for (int j = 0; j < 8; j++)
                ta[i][j] = __builtin_amdgcn_mfma_f32_16x16x32_bf16(af[i], bfr[j], ta[i][j], 0, 0, 0);
    }
#pragma unroll
    for (int j = 0; j < 8; j++) {
        const int n = w * 128 + j * 16 + lr;
        const float bv = b1[n];
#pragma unroll
        for (int i = 0; i < 2; i++)
#pragma unroll
            for (int r = 0; r < 4; r++) {
                const int row = i * 16 + lq * 4 + r;
                T[row * 520 + n] = f2bf(fmaxf(ta[i][j][r] + bv, 0.f));
            }
    }
    __syncthreads();

    // phase C: h' = C1 + T @ W2T^T + b2  (W frags direct)
    f32x4 oa[2][2];
#pragma unroll
    for (int i = 0; i < 2; i++)
#pragma unroll
        for (int j = 0; j < 2; j++) oa[i][j] = (f32x4){0.f, 0.f, 0.f, 0.f};
#pragma unroll
    for (int k0 = 0; k0 < 512; k0 += 32) {
        short8 af[2], bfr[2];
#pragma unroll
        for (int i = 0; i < 2; i++)
            af[i] = *(const short8*)&T[(i * 16 + lr) * 520 + k0 + lq * 8];
#pragma unroll
        for (int j = 0; j < 2; j++)
            bfr[j] = *(const short8*)(W2T + (size_t)(w * 32 + j * 16 + lr) * 512 + k0 + lq * 8);
#pragma unroll
        for (int i = 0; i < 2; i++)
#pragma unroll
            for (int j = 0; j < 2; j++)
                oa[i][j] = __builtin_amdgcn_mfma_f32_16x16x32_bf16(af[i], bfr[j], oa[i][j], 0, 0, 0);
    }
#pragma unroll
    for (int j = 0; j < 2; j++) {
        const int n = w * 32 + j * 16 + lr;
        const float bv = b2[n];
        float psum = 0.f;
#pragma unroll
        for (int i = 0; i < 2; i++)
#pragma unroll
            for (int r = 0; r < 4; r++) {
                const int row = i * 16 + lq * 4 + r;
                const float v = oa[i][j][r] + bv + c1[i][j][r];
                psum += v;
                hf[(size_t)(m0 + row) * 128 + n] = v;
                hb[(size_t)(m0 + row) * 128 + n] = f2bf(v);
            }
        if (accum) {
            psum += __shfl_xor(psum, 16);
            psum += __shfl_xor(psum, 32);
            if (lq == 0) atomicAdd(&pbsum[(m0 >> 9) * 128 + n], psum);
        }
    }
}

// ------------- readout: 512 blocks, 32 rows each (unchanged from R11) -------------
__global__ __launch_bounds__(256) void readout_kernel(const float* __restrict__ h,
                                                      const float* __restrict__ pbsum,
                                                      const float* __restrict__ Wp,
                                                      const float* __restrict__ Wr,
                                                      const float* __restrict__ br,
                                                      float* __restrict__ out) {
    const int u = blockIdx.x;
    const int b = u >> 4;
    const int m0 = u * 32;
    const int t = threadIdx.x;
    __shared__ float pooled[128];
    __shared__ float rp[128];
    __shared__ float pb3[3];
    if (t < 128) pooled[t] = pbsum[b * 128 + t] * (1.0f / 512.0f);
    __syncthreads();
    if (t < 128) {
        float a = 0.f;
        for (int dd = 0; dd < 128; dd++) a += pooled[dd] * Wp[dd * 128 + t];
        rp[t] = fmaxf(a, 0.f);
    }
    __syncthreads();
    if (t < OUT_DIM) {
        float a = br[t];
        for (int j = 0; j < 128; j++) a += rp[j] * Wr[j * 3 + t];
        pb3[t] = a;
    }
    __syncthreads();
    const int j = t & 7;
    const int row = m0 + (t >> 3);
    const float* hr = h + (size_t)row * 128 + j * 16;
    float a0 = 0.f, a1 = 0.f, a2o = 0.f;
#pragma unroll
    for (int dd = 0; dd < 16; dd++) {
        const float v = fmaxf(hr[dd], 0.f);
        const float* wr = Wr + (size_t)(128 + j * 16 + dd) * 3;
        a0 += v * wr[0]; a1 += v * wr[1]; a2o += v * wr[2];
    }
#pragma unroll
    for (int off = 4; off; off >>= 1) {
        a0 += __shfl_down(a0, off, 8);
        a1 += __shfl_down(a1, off, 8);
        a2o += __shfl_down(a2o, off, 8);
    }
    if (j == 0) {
        out[(size_t)row * 3 + 0] = a0 + pb3[0];
        out[(size_t)row * 3 + 1] = a1 + pb3[1];
        out[(size_t)row * 3 + 2] = a2o + pb3[2];
    }
}

extern "C" void kernel_launch(void* const* d_in, const int* in_sizes, int n_in,
                              void* d_out, int out_size, void* d_ws, size_t ws_size,
                              hipStream_t stream) {
    const float* x    = (const float*)d_in[0];
    const int*   mask = (const int*)d_in[1];
    const float* We   = (const float*)d_in[2];
    const float* Wq   = (const float*)d_in[3];
    const float* Wk   = (const float*)d_in[4];
    const float* Wv   = (const float*)d_in[5];
    const float* Wout = (const float*)d_in[6];
    const float* Wff1 = (const float*)d_in[7];
    const float* bff1 = (const float*)d_in[8];
    const float* Wff2 = (const float*)d_in[9];
    const float* bff2 = (const float*)d_in[10];
    const float* Wp   = (const float*)d_in[11];
    const float* Wr   = (const float*)d_in[12];
    const float* br   = (const float*)d_in[13];
    float* out = (float*)d_out;

    char* ws = (char*)d_ws;
    unsigned long long* pm64 = (unsigned long long*)(ws + 0);        // 1 MiB
    const uint_t* pm32       = (const uint_t*)(ws + 0);
    ushort_t* wqkvT = (ushort_t*)(ws + 1048576);
    ushort_t* woutT = (ushort_t*)(ws + 1343488);
    ushort_t* wff1T = (ushort_t*)(ws + 1441792);
    ushort_t* wff2T = (ushort_t*)(ws + 1835008);
    float*    pbsum = (float*)(ws + 2228224);                        // 16 KiB pooled sums
    float*    hbuf  = (float*)(ws + 4194304);                        // 8 MiB fp32 residual
    ushort_t* hb16  = (ushort_t*)(ws + 12582912);                    // 4 MiB bf16 mirror
    ushort_t* a16   = (ushort_t*)(ws + 41943040);                    // 4 MiB attn out

    preproc_kernel<<<PM_BLK + RQ_BLK + TW_BLK + T1_BLK + T2_BLK + PB_BLK + EM_BLK, 256, 0, stream>>>(
        mask, pm64, Wq, Wk, Wv, wqkvT, Wout, woutT, Wff1, wff1T, Wff2, wff2T,
        pbsum, x, We, hbuf, hb16);

    for (int l = 0; l < L_LAYERS; l++) {
        qkv_attn_kernel<<<512, 512, 0, stream>>>(
            hb16, wqkvT + (size_t)l * 384 * 128, pm32, a16);
        tail_kernel<<<M_ROWS / 32, 256, 0, stream>>>(
            a16, woutT + (size_t)l * 128 * 128, wff1T + (size_t)l * 512 * 128,
            wff2T + (size_t)l * 128 * 512, bff1 + l * 512, bff2 + l * 128,
            hbuf, hb16, pbsum, (l == L_LAYERS - 1) ? 1 : 0);
    }

    readout_kernel<<<512, 256, 0, stream>>>(hbuf, pbsum, Wp, Wr, br, out);
}

// Round 13
// 307.601 us; speedup vs baseline: 1.0426x; 1.0426x over previous
//
#include <hip/hip_runtime.h>
#include <cstdint>
#include <cstddef>

#define L_LAYERS 3
#define H_HEADS 8
#define D_EMB 128
#define DKV 16
#define FF_DIM 512
#define B_BATCH 32
#define N_SEQ 512
#define F_INP 16
#define OUT_DIM 3
#define M_ROWS (B_BATCH * N_SEQ)   // 16384

typedef unsigned short ushort_t;
typedef unsigned int uint_t;
typedef __attribute__((ext_vector_type(8))) short short8;
typedef __attribute__((ext_vector_type(4))) float f32x4;
typedef __attribute__((ext_vector_type(16))) float f32x16;

__device__ inline ushort_t f2bf(float x) {   // RNE float->bf16
    union { float f; uint_t u; } v; v.f = x;
    uint_t r = v.u + 0x7fffu + ((v.u >> 16) & 1u);
    return (ushort_t)(r >> 16);
}

__device__ inline uint_t pack2bf(float a, float b) {  // RNE pack: lo=a, hi=b
    union { float f; uint_t u; } ua, ub;
    ua.f = a; ub.f = b;
    uint_t ra = ua.u + 0x7fffu + ((ua.u >> 16) & 1u);
    uint_t rb = ub.u + 0x7fffu + ((ub.u >> 16) & 1u);
    return (ra >> 16) | (rb & 0xffff0000u);
}

__device__ inline void gload16(const void* g, void* l) {
    __builtin_amdgcn_global_load_lds(
        (const __attribute__((address_space(1))) unsigned int*)g,
        (__attribute__((address_space(3))) unsigned int*)l, 16, 0, 0);
}

// ---------------- fused preprocessing (+ pbsum zeroing) ----------------
#define PM_BLK 32768
#define RQ_BLK 576
#define TW_BLK 192
#define T1_BLK 768
#define T2_BLK 768
#define PB_BLK 16
#define EM_BLK 8192
__global__ __launch_bounds__(256) void preproc_kernel(
        const int* __restrict__ mask, unsigned long long* __restrict__ pm,
        const float* __restrict__ Wq, const float* __restrict__ Wk,
        const float* __restrict__ Wv, ushort_t* __restrict__ wqkvT,
        const float* __restrict__ Wout, ushort_t* __restrict__ woutT,
        const float* __restrict__ Wff1, ushort_t* __restrict__ wff1T,
        const float* __restrict__ Wff2, ushort_t* __restrict__ wff2T,
        float* __restrict__ pbsum,
        const float* __restrict__ x, const float* __restrict__ We,
        float* __restrict__ hf, ushort_t* __restrict__ hb) {
    int bx = blockIdx.x;
    const int tid = threadIdx.x;
    if (bx < PM_BLK) {
        int gid = bx * 256 + tid;
        int v = mask[gid];
        unsigned long long bal = __ballot(v != 0);
        if ((tid & 63) == 0) pm[gid >> 6] = bal;
        return;
    }
    bx -= PM_BLK;
    if (bx < RQ_BLK) {
        int idx = bx * 256 + tid;
        int d = idx & 127;
        int n = (idx >> 7) % 384;
        int l = idx / (384 * 128);
        int proj = n >> 7, hh = (n & 127) >> 4, kk = n & 15;
        const float* src = proj == 0 ? Wq : proj == 1 ? Wk : Wv;
        wqkvT[idx] = f2bf(src[((size_t)(l * 8 + hh) * 128 + d) * 16 + kk]);
        return;
    }
    bx -= RQ_BLK;
    if (bx < TW_BLK + T1_BLK + T2_BLK) {
        const float* src; ushort_t* dst; int R, C;
        if (bx < TW_BLK) { src = Wout; dst = woutT; R = 128; C = 128; }
        else if (bx < TW_BLK + T1_BLK) { src = Wff1; dst = wff1T; R = 128; C = 512; bx -= TW_BLK; }
        else { src = Wff2; dst = wff2T; R = 512; C = 128; bx -= TW_BLK + T1_BLK; }
        int idx = bx * 256 + tid;
        int b = idx / (R * C);
        int rem = idx - b * (R * C);
        int r = rem / C, c = rem - r * C;
        dst[(size_t)b * R * C + (size_t)c * R + r] = f2bf(src[idx]);
        return;
    }
    bx -= TW_BLK + T1_BLK + T2_BLK;
    if (bx < PB_BLK) {
        pbsum[bx * 256 + tid] = 0.f;
        return;
    }
    bx -= PB_BLK;
    {
        const int d = tid & 127;
        const int m = bx * 2 + (tid >> 7);
        const float* xr = x + (size_t)m * 16;
        float acc = 0.f;
#pragma unroll
        for (int k = 0; k < 16; k++) acc += xr[k] * We[k * 128 + d];
        acc = fmaxf(acc, 0.f);
        hf[(size_t)m * 128 + d] = acc;
        hb[(size_t)m * 128 + d] = f2bf(acc);
    }
}

// ---------------- fused QKV-GEMM + flash attention (v2: Ws staged in LDS — R11 known-good) ----------------
// Block = (b,h,half): 512 blocks x 512 thr (8 waves), LDS 59.6 KB -> 2 blocks/CU.
__global__ __launch_bounds__(512, 2) void qkv_attn_kernel(
        const ushort_t* __restrict__ hb,    // [16384][128] bf16
        const ushort_t* __restrict__ WqkvT, // layer slice [384][128] bf16 B^T
        const uint_t* __restrict__ pm,      // packed mask
        ushort_t* __restrict__ Aout) {      // [16384][128] bf16
    __shared__ __align__(16) ushort_t sm[29824];   // 59.6 KB
    ushort_t* Qs  = sm;            // [256][16]
    ushort_t* KF  = sm + 4096;     // 16 tiles * 512
    ushort_t* Vt  = sm + 12288;    // [16][520]
    ushort_t* Ws  = sm + 20608;    // [48][128]   (phase 1)
    ushort_t* Ps  = sm + 20608;    // 8 x 32x36   (phase 2, aliases Ws)

    const int tid = threadIdx.x;
    const int w = tid >> 6, L = tid & 63;
    const int lr = L & 15, lq = L >> 4;
    const int lane31 = L & 31, lhalf = L >> 5;
    const int bx = blockIdx.x;
    const int b = bx >> 4, h = (bx >> 1) & 7, half = bx & 1;

    // ---- stage W slice [48 rows n][128 k]: n<16:Q, 16..31:K, 32..47:V ----
    for (int i = tid; i < 768; i += 512) {
        const int row = i >> 4, cg = i & 15;
        const int proj = row >> 4, kk = row & 15;
        gload16(WqkvT + (size_t)(proj * 128 + h * 16 + kk) * 128 + cg * 8, &Ws[i * 8]);
    }
    __syncthreads();

    // ---- QKV GEMM: A-fragments direct from global (L2-hot hb), Ws from LDS, no barriers ----
    const ushort_t* Ab = hb + (size_t)b * 512 * 128;
    for (int mc = 0; mc < 4; mc++) {
        f32x4 acc[3];
#pragma unroll
        for (int j = 0; j < 3; j++) acc[j] = (f32x4){0.f, 0.f, 0.f, 0.f};
#pragma unroll
        for (int k0 = 0; k0 < 128; k0 += 32) {
            short8 af = *(const short8*)(Ab + (size_t)(mc * 128 + w * 16 + lr) * 128 + k0 + lq * 8);
#pragma unroll
            for (int j = 0; j < 3; j++) {
                short8 bf = *(const short8*)&Ws[(j * 16 + lr) * 128 + k0 + lq * 8];
                acc[j] = __builtin_amdgcn_mfma_f32_16x16x32_bf16(af, bf, acc[j], 0, 0, 0);
            }
        }
        // epilogue: C layout col = j*16+lr, row = lq*4+r
        const int rbase = mc * 128 + w * 16 + lq * 4;
#pragma unroll
        for (int r = 0; r < 4; r++) {
            const int key = rbase + r;
            KF[(key >> 5) * 512 + ((lr >> 3) * 32 + (key & 31)) * 8 + (lr & 7)] = f2bf(acc[1][r]);
            Vt[lr * 520 + key] = f2bf(acc[2][r]);
        }
        if ((mc >> 1) == half) {
            const int qb = (mc & 1) * 128 + w * 16 + lq * 4;
#pragma unroll
            for (int r = 0; r < 4; r++)
                Qs[(qb + r) * 16 + lr] = f2bf(acc[0][r] * 0.25f);
        }
    }
    __syncthreads();

    // ---- phase 2: v4 attention; wave owns 32 queries ----
    const int q0g = half * 256 + w * 32;
    const short8 qf = *(const short8*)&Qs[(w * 32 + lane31) * 16 + lhalf * 8];
    const uint_t* pmr = pm + (size_t)(b * 512 + q0g + lane31) * 16;
    const uint4 mwa = *(const uint4*)(pmr);
    const uint4 mwb = *(const uint4*)(pmr + 4);
    const uint4 mwc = *(const uint4*)(pmr + 8);
    const uint4 mwd = *(const uint4*)(pmr + 12);
    const uint_t mw[16] = {mwa.x, mwa.y, mwa.z, mwa.w, mwb.x, mwb.y, mwb.z, mwb.w,
                           mwc.x, mwc.y, mwc.z, mwc.w, mwd.x, mwd.y, mwd.z, mwd.w};
    const f32x16 zero16 = (f32x16)(0.f);

    float mx = -1e30f;
#pragma unroll
    for (int t = 0; t < 16; t++) {
        short8 kf = *(const short8*)&KF[t * 512 + L * 8];
        f32x16 s = __builtin_amdgcn_mfma_f32_32x32x16_bf16(kf, qf, zero16, 0, 0, 0);
#pragma unroll
        for (int r = 0; r < 16; r++) mx = fmaxf(mx, s[r]);
    }
    mx = fmaxf(mx, __shfl_xor(mx, 32));

    float lsum = 0.f;
    f32x4 oacc0 = (f32x4){0.f, 0.f, 0.f, 0.f};
    f32x4 oacc1 = (f32x4){0.f, 0.f, 0.f, 0.f};
#pragma unroll
    for (int t = 0; t < 16; t++) {
        short8 kf = *(const short8*)&KF[t * 512 + L * 8];
        f32x16 s = __builtin_amdgcn_mfma_f32_32x32x16_bf16(kf, qf, zero16, 0, 0, 0);
        const uint_t word = mw[t];
#pragma unroll
        for (int r = 0; r < 16; r++) {
            const int keyl = (r & 3) + 8 * (r >> 2) + 4 * lhalf;
            const float e = __expf(s[r] - mx);
            const float pv = (word & (1u << keyl)) ? e : 0.f;
            s[r] = pv;
            lsum += pv;
        }
#pragma unroll
        for (int g = 0; g < 4; g++) {
            const uint_t lo = pack2bf(s[g * 4 + 0], s[g * 4 + 1]);
            const uint_t hi = pack2bf(s[g * 4 + 2], s[g * 4 + 3]);
            *(uint2*)&Ps[w * 1152 + lane31 * 36 + g * 8 + 4 * lhalf] = make_uint2(lo, hi);
        }
        short8 vb = *(const short8*)&Vt[lr * 520 + t * 32 + lq * 8];
        short8 pa0 = *(const short8*)&Ps[w * 1152 + lr * 36 + lq * 8];
        short8 pa1 = *(const short8*)&Ps[w * 1152 + (16 + lr) * 36 + lq * 8];
        oacc0 = __builtin_amdgcn_mfma_f32_16x16x32_bf16(pa0, vb, oacc0, 0, 0, 0);
        oacc1 = __builtin_amdgcn_mfma_f32_16x16x32_bf16(pa1, vb, oacc1, 0, 0, 0);
    }
    lsum += __shfl_xor(lsum, 32);

#pragma unroll
    for (int qa = 0; qa < 2; qa++) {
        const f32x4 oa = qa ? oacc1 : oacc0;
#pragma unroll
        for (int rr = 0; rr < 4; rr++) {
            const int qloc = qa * 16 + lq * 4 + rr;
            const float ls = __shfl(lsum, qloc, 64);
            Aout[(size_t)(b * 512 + q0g + qloc) * 128 + h * 16 + lr] = f2bf(oa[rr] / ls);
        }
    }
}

// ---------------- fused layer tail v3 (R12 — measured win): zero staging, 2 barriers ----------------
__global__ __launch_bounds__(256, 2) void tail_kernel(
        const ushort_t* __restrict__ A,     // a16 [16384][128]
        const ushort_t* __restrict__ WoT,   // [128 n][128 k]
        const ushort_t* __restrict__ W1T,   // [512 n][128 k]
        const ushort_t* __restrict__ W2T,   // [128 n][512 k]
        const float* __restrict__ b1,
        const float* __restrict__ b2,
        float* __restrict__ hf, ushort_t* __restrict__ hb,
        float* __restrict__ pbsum, int accum) {
    __shared__ __align__(16) ushort_t C1b[32 * 136];   // 8.7 KB
    __shared__ __align__(16) ushort_t T[32 * 520];     // 33.3 KB

    const int tid = threadIdx.x;
    const int w = tid >> 6, l = tid & 63;
    const int lr = l & 15, lq = l >> 4;
    const int m0 = blockIdx.x * 32;

    // phase A: C1 = a16 @ WoT^T + h   (frags direct from global)
    f32x4 c1a[2][2];
#pragma unroll
    for (int i = 0; i < 2; i++)
#pragma unroll
        for (int j = 0; j < 2; j++) c1a[i][j] = (f32x4){0.f, 0.f, 0.f, 0.f};
#pragma unroll
    for (int k0 = 0; k0 < 128; k0 += 32) {
        short8 af[2], bfr[2];
#pragma unroll
        for (int i = 0; i < 2; i++)
            af[i] = *(const short8*)(A + (size_t)(m0 + i * 16 + lr) * 128 + k0 + lq * 8);
#pragma unroll
        for (int j = 0; j < 2; j++)
            bfr[j] = *(const short8*)(WoT + (size_t)(w * 32 + j * 16 + lr) * 128 + k0 + lq * 8);
#pragma unroll
        for (int i = 0; i < 2; i++)
#pragma unroll
            for (int j = 0; j < 2; j++)
                c1a[i][j] = __builtin_amdgcn_mfma_f32_16x16x32_bf16(af[i], bfr[j], c1a[i][j], 0, 0, 0);
    }
    float c1[2][2][4];
#pragma unroll
    for (int i = 0; i < 2; i++)
#pragma unroll
        for (int r = 0; r < 4; r++) {
            const int row = i * 16 + lq * 4 + r;
#pragma unroll
            for (int j = 0; j < 2; j++) {
                const int n = w * 32 + j * 16 + lr;
                const float v = c1a[i][j][r] + hf[(size_t)(m0 + row) * 128 + n];
                c1[i][j][r] = v;
                C1b[row * 136 + n] = f2bf(v);
            }
        }
    __syncthreads();

    // phase B: T = relu(C1 @ W1T^T + b1)  (W frags direct)
    f32x4 ta[2][8];
#pragma unroll
    for (int i = 0; i < 2; i++)
#pragma unroll
        for (int j = 0; j < 8; j++) ta[i][j] = (f32x4){0.f, 0.f, 0.f, 0.f};
#pragma unroll
    for (int k0 = 0; k0 < 128; k0 += 32) {
        short8 af[2], bfr[8];
#pragma unroll
        for (int i = 0; i < 2; i++)
            af[i] = *(const short8*)&C1b[(i * 16 + lr) * 136 + k0 + lq * 8];
#pragma unroll
        for (int j = 0; j < 8; j++)
            bfr[j] = *(const short8*)(W1T + (size_t)(w * 128 + j * 16 + lr) * 128 + k0 + lq * 8);
#pragma unroll
        for (int i = 0; i < 2; i++)
#pragma unroll
            for (int j = 0; j < 8; j++)
                ta[i][j] = __builtin_amdgcn_mfma_f32_16x16x32_bf16(af[i], bfr[j], ta[i][j], 0, 0, 0);
    }
#pragma unroll
    for (int j = 0; j < 8; j++) {
        const int n = w * 128 + j * 16 + lr;
        const float bv = b1[n];
#pragma unroll
        for (int i = 0; i < 2; i++)
#pragma unroll
            for (int r = 0; r < 4; r++) {
                const int row = i * 16 + lq * 4 + r;
                T[row * 520 + n] = f2bf(fmaxf(ta[i][j][r] + bv, 0.f));
            }
    }
    __syncthreads();

    // phase C: h' = C1 + T @ W2T^T + b2  (W frags direct)
    f32x4 oa[2][2];
#pragma unroll
    for (int i = 0; i < 2; i++)
#pragma unroll
        for (int j = 0; j < 2; j++) oa[i][j] = (f32x4){0.f, 0.f, 0.f, 0.f};
#pragma unroll
    for (int k0 = 0; k0 < 512; k0 += 32) {
        short8 af[2], bfr[2];
#pragma unroll
        for (int i = 0; i < 2; i++)
            af[i] = *(const short8*)&T[(i * 16 + lr) * 520 + k0 + lq * 8];
#pragma unroll
        for (int j = 0; j < 2; j++)
            bfr[j] = *(const short8*)(W2T + (size_t)(w * 32 + j * 16 + lr) * 512 + k0 + lq * 8);
#pragma unroll
        for (int i = 0; i < 2; i++)
#pragma unroll
            for (int j = 0; j < 2; j++)
                oa[i][j] = __builtin_amdgcn_mfma_f32_16x16x32_bf16(af[i], bfr[j], oa[i][j], 0, 0, 0);
    }
#pragma unroll
    for (int j = 0; j < 2; j++) {
        const int n = w * 32 + j * 16 + lr;
        const float bv = b2[n];
        float psum = 0.f;
#pragma unroll
        for (int i = 0; i < 2; i++)
#pragma unroll
            for (int r = 0; r < 4; r++) {
                const int row = i * 16 + lq * 4 + r;
                const float v = oa[i][j][r] + bv + c1[i][j][r];
                psum += v;
                hf[(size_t)(m0 + row) * 128 + n] = v;
                hb[(size_t)(m0 + row) * 128 + n] = f2bf(v);
            }
        if (accum) {
            psum += __shfl_xor(psum, 16);
            psum += __shfl_xor(psum, 32);
            if (lq == 0) atomicAdd(&pbsum[(m0 >> 9) * 128 + n], psum);
        }
    }
}

// ------------- readout: 512 blocks, 32 rows each (unchanged) -------------
__global__ __launch_bounds__(256) void readout_kernel(const float* __restrict__ h,
                                                      const float* __restrict__ pbsum,
                                                      const float* __restrict__ Wp,
                                                      const float* __restrict__ Wr,
                                                      const float* __restrict__ br,
                                                      float* __restrict__ out) {
    const int u = blockIdx.x;
    const int b = u >> 4;
    const int m0 = u * 32;
    const int t = threadIdx.x;
    __shared__ float pooled[128];
    __shared__ float rp[128];
    __shared__ float pb3[3];
    if (t < 128) pooled[t] = pbsum[b * 128 + t] * (1.0f / 512.0f);
    __syncthreads();
    if (t < 128) {
        float a = 0.f;
        for (int dd = 0; dd < 128; dd++) a += pooled[dd] * Wp[dd * 128 + t];
        rp[t] = fmaxf(a, 0.f);
    }
    __syncthreads();
    if (t < OUT_DIM) {
        float a = br[t];
        for (int j = 0; j < 128; j++) a += rp[j] * Wr[j * 3 + t];
        pb3[t] = a;
    }
    __syncthreads();
    const int j = t & 7;
    const int row = m0 + (t >> 3);
    const float* hr = h + (size_t)row * 128 + j * 16;
    float a0 = 0.f, a1 = 0.f, a2o = 0.f;
#pragma unroll
    for (int dd = 0; dd < 16; dd++) {
        const float v = fmaxf(hr[dd], 0.f);
        const float* wr = Wr + (size_t)(128 + j * 16 + dd) * 3;
        a0 += v * wr[0]; a1 += v * wr[1]; a2o += v * wr[2];
    }
#pragma unroll
    for (int off = 4; off; off >>= 1) {
        a0 += __shfl_down(a0, off, 8);
        a1 += __shfl_down(a1, off, 8);
        a2o += __shfl_down(a2o, off, 8);
    }
    if (j == 0) {
        out[(size_t)row * 3 + 0] = a0 + pb3[0];
        out[(size_t)row * 3 + 1] = a1 + pb3[1];
        out[(size_t)row * 3 + 2] = a2o + pb3[2];
    }
}

extern "C" void kernel_launch(void* const* d_in, const int* in_sizes, int n_in,
                              void* d_out, int out_size, void* d_ws, size_t ws_size,
                              hipStream_t stream) {
    const float* x    = (const float*)d_in[0];
    const int*   mask = (const int*)d_in[1];
    const float* We   = (const float*)d_in[2];
    const float* Wq   = (const float*)d_in[3];
    const float* Wk   = (const float*)d_in[4];
    const float* Wv   = (const float*)d_in[5];
    const float* Wout = (const float*)d_in[6];
    const float* Wff1 = (const float*)d_in[7];
    const float* bff1 = (const float*)d_in[8];
    const float* Wff2 = (const float*)d_in[9];
    const float* bff2 = (const float*)d_in[10];
    const float* Wp   = (const float*)d_in[11];
    const float* Wr   = (const float*)d_in[12];
    const float* br   = (const float*)d_in[13];
    float* out = (float*)d_out;

    char* ws = (char*)d_ws;
    unsigned long long* pm64 = (unsigned long long*)(ws + 0);        // 1 MiB
    const uint_t* pm32       = (const uint_t*)(ws + 0);
    ushort_t* wqkvT = (ushort_t*)(ws + 1048576);
    ushort_t* woutT = (ushort_t*)(ws + 1343488);
    ushort_t* wff1T = (ushort_t*)(ws + 1441792);
    ushort_t* wff2T = (ushort_t*)(ws + 1835008);
    float*    pbsum = (float*)(ws + 2228224);                        // 16 KiB pooled sums
    float*    hbuf  = (float*)(ws + 4194304);                        // 8 MiB fp32 residual
    ushort_t* hb16  = (ushort_t*)(ws + 12582912);                    // 4 MiB bf16 mirror
    ushort_t* a16   = (ushort_t*)(ws + 41943040);                    // 4 MiB attn out

    preproc_kernel<<<PM_BLK + RQ_BLK + TW_BLK + T1_BLK + T2_BLK + PB_BLK + EM_BLK, 256, 0, stream>>>(
        mask, pm64, Wq, Wk, Wv, wqkvT, Wout, woutT, Wff1, wff1T, Wff2, wff2T,
        pbsum, x, We, hbuf, hb16);

    for (int l = 0; l < L_LAYERS; l++) {
        qkv_attn_kernel<<<512, 512, 0, stream>>>(
            hb16, wqkvT + (size_t)l * 384 * 128, pm32, a16);
        tail_kernel<<<M_ROWS / 32, 256, 0, stream>>>(
            a16, woutT + (size_t)l * 128 * 128, wff1T + (size_t)l * 512 * 128,
            wff2T + (size_t)l * 128 * 512, bff1 + l * 512, bff2 + l * 128,
            hbuf, hb16, pbsum, (l == L_LAYERS - 1) ? 1 : 0);
    }

    readout_kernel<<<512, 256, 0, stream>>>(hbuf, pbsum, Wp, Wr, br, out);
}

// Round 14
// 280.705 us; speedup vs baseline: 1.1425x; 1.0958x over previous
//
#include <hip/hip_runtime.h>
#include <cstdint>
#include <cstddef>

#define L_LAYERS 3
#define H_HEADS 8
#define D_EMB 128
#define DKV 16
#define FF_DIM 512
#define B_BATCH 32
#define N_SEQ 512
#define F_INP 16
#define OUT_DIM 3
#define M_ROWS (B_BATCH * N_SEQ)   // 16384
#define QSCALE 0.3606737602222409f // 0.25 * log2(e): scores in log2 domain

typedef unsigned short ushort_t;
typedef unsigned int uint_t;
typedef __attribute__((ext_vector_type(8))) short short8;
typedef __attribute__((ext_vector_type(4))) float f32x4;
typedef __attribute__((ext_vector_type(16))) float f32x16;

__device__ inline ushort_t f2bf(float x) {   // RNE float->bf16
    union { float f; uint_t u; } v; v.f = x;
    uint_t r = v.u + 0x7fffu + ((v.u >> 16) & 1u);
    return (ushort_t)(r >> 16);
}

__device__ inline uint_t pack2bf_tr(float a, float b) {  // truncating pack: lo=a, hi=b
    union { float f; uint_t u; } ua, ub;
    ua.f = a; ub.f = b;
    return (ua.u >> 16) | (ub.u & 0xffff0000u);
}

__device__ inline float exp2fast(float x) {   // raw v_exp_f32 (2^x)
#if __has_builtin(__builtin_amdgcn_exp2f)
    return __builtin_amdgcn_exp2f(x);
#else
    float r; __asm__("v_exp_f32 %0, %1" : "=v"(r) : "v"(x)); return r;
#endif
}

__device__ inline void gload16(const void* g, void* l) {
    __builtin_amdgcn_global_load_lds(
        (const __attribute__((address_space(1))) unsigned int*)g,
        (__attribute__((address_space(3))) unsigned int*)l, 16, 0, 0);
}

// ---------------- fused preprocessing (+ pbsum zeroing) ----------------
#define PM_BLK 32768
#define RQ_BLK 576
#define TW_BLK 192
#define T1_BLK 768
#define T2_BLK 768
#define PB_BLK 16
#define EM_BLK 8192
__global__ __launch_bounds__(256) void preproc_kernel(
        const int* __restrict__ mask, unsigned long long* __restrict__ pm,
        const float* __restrict__ Wq, const float* __restrict__ Wk,
        const float* __restrict__ Wv, ushort_t* __restrict__ wqkvT,
        const float* __restrict__ Wout, ushort_t* __restrict__ woutT,
        const float* __restrict__ Wff1, ushort_t* __restrict__ wff1T,
        const float* __restrict__ Wff2, ushort_t* __restrict__ wff2T,
        float* __restrict__ pbsum,
        const float* __restrict__ x, const float* __restrict__ We,
        float* __restrict__ hf, ushort_t* __restrict__ hb) {
    int bx = blockIdx.x;
    const int tid = threadIdx.x;
    if (bx < PM_BLK) {
        int gid = bx * 256 + tid;
        int v = mask[gid];
        unsigned long long bal = __ballot(v != 0);
        if ((tid & 63) == 0) pm[gid >> 6] = bal;
        return;
    }
    bx -= PM_BLK;
    if (bx < RQ_BLK) {
        int idx = bx * 256 + tid;
        int d = idx & 127;
        int n = (idx >> 7) % 384;
        int l = idx / (384 * 128);
        int proj = n >> 7, hh = (n & 127) >> 4, kk = n & 15;
        const float* src = proj == 0 ? Wq : proj == 1 ? Wk : Wv;
        wqkvT[idx] = f2bf(src[((size_t)(l * 8 + hh) * 128 + d) * 16 + kk]);
        return;
    }
    bx -= RQ_BLK;
    if (bx < TW_BLK + T1_BLK + T2_BLK) {
        const float* src; ushort_t* dst; int R, C;
        if (bx < TW_BLK) { src = Wout; dst = woutT; R = 128; C = 128; }
        else if (bx < TW_BLK + T1_BLK) { src = Wff1; dst = wff1T; R = 128; C = 512; bx -= TW_BLK; }
        else { src = Wff2; dst = wff2T; R = 512; C = 128; bx -= TW_BLK + T1_BLK; }
        int idx = bx * 256 + tid;
        int b = idx / (R * C);
        int rem = idx - b * (R * C);
        int r = rem / C, c = rem - r * C;
        dst[(size_t)b * R * C + (size_t)c * R + r] = f2bf(src[idx]);
        return;
    }
    bx -= TW_BLK + T1_BLK + T2_BLK;
    if (bx < PB_BLK) {
        pbsum[bx * 256 + tid] = 0.f;
        return;
    }
    bx -= PB_BLK;
    {
        const int d = tid & 127;
        const int m = bx * 2 + (tid >> 7);
        const float* xr = x + (size_t)m * 16;
        float acc = 0.f;
#pragma unroll
        for (int k = 0; k < 16; k++) acc += xr[k] * We[k * 128 + d];
        acc = fmaxf(acc, 0.f);
        hf[(size_t)m * 128 + d] = acc;
        hb[(size_t)m * 128 + d] = f2bf(acc);
    }
}

// ---------------- fused QKV-GEMM + flash attention v4 ----------------
// Block = (b,h,half): 512 blocks x 512 thr (8 waves). LDS 53.5 KB -> 3 blocks/CU
// (Ps aliases Qs after qf-read barrier; Ws aliases Ps region across the phase barrier).
// exp2-domain scores (Q prescaled by 0.25*log2e); lsum via ones-MFMA (in-lane normalize).
__global__ __launch_bounds__(512, 2) void qkv_attn_kernel(
        const ushort_t* __restrict__ hb,    // [16384][128] bf16
        const ushort_t* __restrict__ WqkvT, // layer slice [384][128] bf16 B^T
        const uint_t* __restrict__ pm,      // packed mask
        ushort_t* __restrict__ Aout) {      // [16384][128] bf16
    __shared__ __align__(16) ushort_t sm[26752];   // 53.5 KB
    ushort_t* KF = sm;            // 16 tiles * 512        [0, 8192)
    ushort_t* Vt = sm + 8192;     // [16][520]             [8192, 16512)
    ushort_t* Qs = sm + 16512;    // [256][16]             [16512, 20608)  phase 1+qf
    ushort_t* Ws = sm + 20608;    // [48][128]             [20608, 26752)  phase 1 only
    ushort_t* Ps = sm + 16512;    // 8 x 32x36 = 9216      [16512, 25728)  phase 2, aliases Qs+Ws

    const int tid = threadIdx.x;
    const int w = tid >> 6, L = tid & 63;
    const int lr = L & 15, lq = L >> 4;
    const int lane31 = L & 31, lhalf = L >> 5;
    const int bx = blockIdx.x;
    const int b = bx >> 4, h = (bx >> 1) & 7, half = bx & 1;

    // ---- stage W slice [48 rows n][128 k]: n<16:Q, 16..31:K, 32..47:V ----
    for (int i = tid; i < 768; i += 512) {
        const int row = i >> 4, cg = i & 15;
        const int proj = row >> 4, kk = row & 15;
        gload16(WqkvT + (size_t)(proj * 128 + h * 16 + kk) * 128 + cg * 8, &Ws[i * 8]);
    }
    __syncthreads();

    // ---- QKV GEMM: A-frags direct from global (L2-hot hb), Ws from LDS ----
    const ushort_t* Ab = hb + (size_t)b * 512 * 128;
    for (int mc = 0; mc < 4; mc++) {
        f32x4 acc[3];
#pragma unroll
        for (int j = 0; j < 3; j++) acc[j] = (f32x4){0.f, 0.f, 0.f, 0.f};
#pragma unroll
        for (int k0 = 0; k0 < 128; k0 += 32) {
            short8 af = *(const short8*)(Ab + (size_t)(mc * 128 + w * 16 + lr) * 128 + k0 + lq * 8);
#pragma unroll
            for (int j = 0; j < 3; j++) {
                short8 bf = *(const short8*)&Ws[(j * 16 + lr) * 128 + k0 + lq * 8];
                acc[j] = __builtin_amdgcn_mfma_f32_16x16x32_bf16(af, bf, acc[j], 0, 0, 0);
            }
        }
        // epilogue: C layout col = j*16+lr, row = lq*4+r
        const int rbase = mc * 128 + w * 16 + lq * 4;
#pragma unroll
        for (int r = 0; r < 4; r++) {
            const int key = rbase + r;
            KF[(key >> 5) * 512 + ((lr >> 3) * 32 + (key & 31)) * 8 + (lr & 7)] = f2bf(acc[1][r]);
            Vt[lr * 520 + key] = f2bf(acc[2][r]);
        }
        if ((mc >> 1) == half) {
            const int qb = (mc & 1) * 128 + w * 16 + lq * 4;
#pragma unroll
            for (int r = 0; r < 4; r++)
                Qs[(qb + r) * 16 + lr] = f2bf(acc[0][r] * QSCALE);
        }
    }
    __syncthreads();

    // ---- read Q frag + mask, then free Qs for Ps aliasing ----
    const int q0g = half * 256 + w * 32;
    const short8 qf = *(const short8*)&Qs[(w * 32 + lane31) * 16 + lhalf * 8];
    const uint_t* pmr = pm + (size_t)(b * 512 + q0g + lane31) * 16;
    const uint4 mwa = *(const uint4*)(pmr);
    const uint4 mwb = *(const uint4*)(pmr + 4);
    const uint4 mwc = *(const uint4*)(pmr + 8);
    const uint4 mwd = *(const uint4*)(pmr + 12);
    const uint_t mw[16] = {mwa.x, mwa.y, mwa.z, mwa.w, mwb.x, mwb.y, mwb.z, mwb.w,
                           mwc.x, mwc.y, mwc.z, mwc.w, mwd.x, mwd.y, mwd.z, mwd.w};
    __syncthreads();   // all qf reads done; Qs region now writable as Ps

    const f32x16 zero16 = (f32x16)(0.f);
    short8 vone;
#pragma unroll
    for (int i = 0; i < 8; i++) vone[i] = (short)0x3F80;   // bf16 1.0

    // ---- pass 1: per-q raw max (scores already in log2 domain) ----
    float mx = -1e30f;
#pragma unroll
    for (int t = 0; t < 16; t++) {
        short8 kf = *(const short8*)&KF[t * 512 + L * 8];
        f32x16 s = __builtin_amdgcn_mfma_f32_32x32x16_bf16(kf, qf, zero16, 0, 0, 0);
#pragma unroll
        for (int r = 0; r < 16; r++) mx = fmaxf(mx, s[r]);
    }
    mx = fmaxf(mx, __shfl_xor(mx, 32));

    // ---- pass 2: exp2 + mask + pack + PV + lsum-MFMA ----
    f32x4 oacc0 = (f32x4){0.f, 0.f, 0.f, 0.f};
    f32x4 oacc1 = (f32x4){0.f, 0.f, 0.f, 0.f};
    f32x4 lacc0 = (f32x4){0.f, 0.f, 0.f, 0.f};
    f32x4 lacc1 = (f32x4){0.f, 0.f, 0.f, 0.f};
#pragma unroll
    for (int t = 0; t < 16; t++) {
        short8 kf = *(const short8*)&KF[t * 512 + L * 8];
        f32x16 s = __builtin_amdgcn_mfma_f32_32x32x16_bf16(kf, qf, zero16, 0, 0, 0);
        const uint_t word = mw[t];
#pragma unroll
        for (int r = 0; r < 16; r++) {
            const int keyl = (r & 3) + 8 * (r >> 2) + 4 * lhalf;
            const float e = exp2fast(s[r] - mx);
            s[r] = (word & (1u << keyl)) ? e : 0.f;
        }
#pragma unroll
        for (int g = 0; g < 4; g++) {
            const uint_t lo = pack2bf_tr(s[g * 4 + 0], s[g * 4 + 1]);
            const uint_t hi = pack2bf_tr(s[g * 4 + 2], s[g * 4 + 3]);
            *(uint2*)&Ps[w * 1152 + lane31 * 36 + g * 8 + 4 * lhalf] = make_uint2(lo, hi);
        }
        short8 vb = *(const short8*)&Vt[lr * 520 + t * 32 + lq * 8];
        short8 pa0 = *(const short8*)&Ps[w * 1152 + lr * 36 + lq * 8];
        short8 pa1 = *(const short8*)&Ps[w * 1152 + (16 + lr) * 36 + lq * 8];
        oacc0 = __builtin_amdgcn_mfma_f32_16x16x32_bf16(pa0, vb, oacc0, 0, 0, 0);
        oacc1 = __builtin_amdgcn_mfma_f32_16x16x32_bf16(pa1, vb, oacc1, 0, 0, 0);
        lacc0 = __builtin_amdgcn_mfma_f32_16x16x32_bf16(pa0, vone, lacc0, 0, 0, 0);
        lacc1 = __builtin_amdgcn_mfma_f32_16x16x32_bf16(pa1, vone, lacc1, 0, 0, 0);
    }

    // ---- normalize in-lane (lacc lane-mapping matches oacc exactly) ----
#pragma unroll
    for (int qa = 0; qa < 2; qa++) {
        const f32x4 oa = qa ? oacc1 : oacc0;
        const f32x4 la = qa ? lacc1 : lacc0;
#pragma unroll
        for (int rr = 0; rr < 4; rr++) {
            const int qloc = qa * 16 + lq * 4 + rr;
            Aout[(size_t)(b * 512 + q0g + qloc) * 128 + h * 16 + lr] = f2bf(oa[rr] / la[rr]);
        }
    }
}

// ---------------- fused layer tail (R11 staged version — measured best) ----------------
__global__ __launch_bounds__(256, 2) void tail_kernel(
        const ushort_t* __restrict__ A,     // a16 [16384][128]
        const ushort_t* __restrict__ WoT,   // [128 n][128 k]
        const ushort_t* __restrict__ W1T,   // [512 n][128 k]
        const ushort_t* __restrict__ W2T,   // [128 n][512 k]
        const float* __restrict__ b1,
        const float* __restrict__ b2,
        float* __restrict__ hf, ushort_t* __restrict__ hb,
        float* __restrict__ pbsum, int accum) {
    __shared__ __align__(16) ushort_t sm[38400];          // 76.8 KB -> 2 blocks/CU
    ushort_t* As  = sm;
    ushort_t* Bs  = sm + 1024;
    ushort_t* C1b = sm + 17408;
    ushort_t* T   = sm + 21760;

    const int tid = threadIdx.x;
    const int w = tid >> 6, l = tid & 63;
    const int lr = l & 15, lq = l >> 4;
    const int srow = (l >> 2);
    const int scol = (l & 3) * 8;
    const int m0 = blockIdx.x * 32;

    // phase A: C1 = a16 @ WoT^T + h
    f32x4 c1a[2][2];
#pragma unroll
    for (int i = 0; i < 2; i++)
#pragma unroll
        for (int j = 0; j < 2; j++) c1a[i][j] = (f32x4){0.f, 0.f, 0.f, 0.f};
    for (int k0 = 0; k0 < 128; k0 += 32) {
        if (w < 2)
            gload16(A + (size_t)(m0 + w * 16 + srow) * 128 + k0 + scol,
                    &As[(w * 16 + srow) * 32 + scol]);
#pragma unroll
        for (int it = 0; it < 2; it++)
            gload16(WoT + (size_t)(it * 64 + w * 16 + srow) * 128 + k0 + scol,
                    &Bs[(it * 64 + w * 16 + srow) * 32 + scol]);
        __syncthreads();
        short8 af[2], bfr[2];
#pragma unroll
        for (int i = 0; i < 2; i++) af[i] = *(const short8*)&As[(i * 16 + lr) * 32 + lq * 8];
#pragma unroll
        for (int j = 0; j < 2; j++) bfr[j] = *(const short8*)&Bs[(w * 32 + j * 16 + lr) * 32 + lq * 8];
#pragma unroll
        for (int i = 0; i < 2; i++)
#pragma unroll
            for (int j = 0; j < 2; j++)
                c1a[i][j] = __builtin_amdgcn_mfma_f32_16x16x32_bf16(af[i], bfr[j], c1a[i][j], 0, 0, 0);
        __syncthreads();
    }
    float c1[2][2][4];
#pragma unroll
    for (int i = 0; i < 2; i++)
#pragma unroll
        for (int r = 0; r < 4; r++) {
            const int row = i * 16 + lq * 4 + r;
#pragma unroll
            for (int j = 0; j < 2; j++) {
                const int n = w * 32 + j * 16 + lr;
                const float v = c1a[i][j][r] + hf[(size_t)(m0 + row) * 128 + n];
                c1[i][j][r] = v;
                C1b[row * 136 + n] = f2bf(v);
            }
        }
    __syncthreads();

    // phase B: T = relu(C1 @ W1T^T + b1)
    f32x4 ta[2][8];
#pragma unroll
    for (int i = 0; i < 2; i++)
#pragma unroll
        for (int j = 0; j < 8; j++) ta[i][j] = (f32x4){0.f, 0.f, 0.f, 0.f};
    for (int k0 = 0; k0 < 128; k0 += 32) {
#pragma unroll
        for (int it = 0; it < 8; it++)
            gload16(W1T + (size_t)(it * 64 + w * 16 + srow) * 128 + k0 + scol,
                    &Bs[(it * 64 + w * 16 + srow) * 32 + scol]);
        __syncthreads();
        short8 af[2], bfr[8];
#pragma unroll
        for (int i = 0; i < 2; i++) af[i] = *(const short8*)&C1b[(i * 16 + lr) * 136 + k0 + lq * 8];
#pragma unroll
        for (int j = 0; j < 8; j++) bfr[j] = *(const short8*)&Bs[(w * 128 + j * 16 + lr) * 32 + lq * 8];
#pragma unroll
        for (int i = 0; i < 2; i++)
#pragma unroll
            for (int j = 0; j < 8; j++)
                ta[i][j] = __builtin_amdgcn_mfma_f32_16x16x32_bf16(af[i], bfr[j], ta[i][j], 0, 0, 0);
        __syncthreads();
    }
#pragma unroll
    for (int j = 0; j < 8; j++) {
        const int n = w * 128 + j * 16 + lr;
        const float bv = b1[n];
#pragma unroll
        for (int i = 0; i < 2; i++)
#pragma unroll
            for (int r = 0; r < 4; r++) {
                const int row = i * 16 + lq * 4 + r;
                T[row * 520 + n] = f2bf(fmaxf(ta[i][j][r] + bv, 0.f));
            }
    }
    __syncthreads();

    // phase C: h' = C1 + T @ W2T^T + b2
    f32x4 oa[2][2];
#pragma unroll
    for (int i = 0; i < 2; i++)
#pragma unroll
        for (int j = 0; j < 2; j++) oa[i][j] = (f32x4){0.f, 0.f, 0.f, 0.f};
    for (int k0 = 0; k0 < 512; k0 += 32) {
#pragma unroll
        for (int it = 0; it < 2; it++)
            gload16(W2T + (size_t)(it * 64 + w * 16 + srow) * 512 + k0 + scol,
                    &Bs[(it * 64 + w * 16 + srow) * 32 + scol]);
        __syncthreads();
        short8 af[2], bfr[2];
#pragma unroll
        for (int i = 0; i < 2; i++) af[i] = *(const short8*)&T[(i * 16 + lr) * 520 + k0 + lq * 8];
#pragma unroll
        for (int j = 0; j < 2; j++) bfr[j] = *(const short8*)&Bs[(w * 32 + j * 16 + lr) * 32 + lq * 8];
#pragma unroll
        for (int i = 0; i < 2; i++)
#pragma unroll
            for (int j = 0; j < 2; j++)
                oa[i][j] = __builtin_amdgcn_mfma_f32_16x16x32_bf16(af[i], bfr[j], oa[i][j], 0, 0, 0);
        __syncthreads();
    }
#pragma unroll
    for (int j = 0; j < 2; j++) {
        const int n = w * 32 + j * 16 + lr;
        const float bv = b2[j * 0 + n];
        float psum = 0.f;
#pragma unroll
        for (int i = 0; i < 2; i++)
#pragma unroll
            for (int r = 0; r < 4; r++) {
                const int row = i * 16 + lq * 4 + r;
                const float v = oa[i][j][r] + bv + c1[i][j][r];
                psum += v;
                hf[(size_t)(m0 + row) * 128 + n] = v;
                hb[(size_t)(m0 + row) * 128 + n] = f2bf(v);
            }
        if (accum) {
            psum += __shfl_xor(psum, 16);
            psum += __shfl_xor(psum, 32);
            if (lq == 0) atomicAdd(&pbsum[(m0 >> 9) * 128 + n], psum);
        }
    }
}

// ------------- readout: 512 blocks, 32 rows each (unchanged) -------------
__global__ __launch_bounds__(256) void readout_kernel(const float* __restrict__ h,
                                                      const float* __restrict__ pbsum,
                                                      const float* __restrict__ Wp,
                                                      const float* __restrict__ Wr,
                                                      const float* __restrict__ br,
                                                      float* __restrict__ out) {
    const int u = blockIdx.x;
    const int b = u >> 4;
    const int m0 = u * 32;
    const int t = threadIdx.x;
    __shared__ float pooled[128];
    __shared__ float rp[128];
    __shared__ float pb3[3];
    if (t < 128) pooled[t] = pbsum[b * 128 + t] * (1.0f / 512.0f);
    __syncthreads();
    if (t < 128) {
        float a = 0.f;
        for (int dd = 0; dd < 128; dd++) a += pooled[dd] * Wp[dd * 128 + t];
        rp[t] = fmaxf(a, 0.f);
    }
    __syncthreads();
    if (t < OUT_DIM) {
        float a = br[t];
        for (int j = 0; j < 128; j++) a += rp[j] * Wr[j * 3 + t];
        pb3[t] = a;
    }
    __syncthreads();
    const int j = t & 7;
    const int row = m0 + (t >> 3);
    const float* hr = h + (size_t)row * 128 + j * 16;
    float a0 = 0.f, a1 = 0.f, a2o = 0.f;
#pragma unroll
    for (int dd = 0; dd < 16; dd++) {
        const float v = fmaxf(hr[dd], 0.f);
        const float* wr = Wr + (size_t)(128 + j * 16 + dd) * 3;
        a0 += v * wr[0]; a1 += v * wr[1]; a2o += v * wr[2];
    }
#pragma unroll
    for (int off = 4; off; off >>= 1) {
        a0 += __shfl_down(a0, off, 8);
        a1 += __shfl_down(a1, off, 8);
        a2o += __shfl_down(a2o, off, 8);
    }
    if (j == 0) {
        out[(size_t)row * 3 + 0] = a0 + pb3[0];
        out[(size_t)row * 3 + 1] = a1 + pb3[1];
        out[(size_t)row * 3 + 2] = a2o + pb3[2];
    }
}

extern "C" void kernel_launch(void* const* d_in, const int* in_sizes, int n_in,
                              void* d_out, int out_size, void* d_ws, size_t ws_size,
                              hipStream_t stream) {
    const float* x    = (const float*)d_in[0];
    const int*   mask = (const int*)d_in[1];
    const float* We   = (const float*)d_in[2];
    const float* Wq   = (const float*)d_in[3];
    const float* Wk   = (const float*)d_in[4];
    const float* Wv   = (const float*)d_in[5];
    const float* Wout = (const float*)d_in[6];
    const float* Wff1 = (const float*)d_in[7];
    const float* bff1 = (const float*)d_in[8];
    const float* Wff2 = (const float*)d_in[9];
    const float* bff2 = (const float*)d_in[10];
    const float* Wp   = (const float*)d_in[11];
    const float* Wr   = (const float*)d_in[12];
    const float* br   = (const float*)d_in[13];
    float* out = (float*)d_out;

    char* ws = (char*)d_ws;
    unsigned long long* pm64 = (unsigned long long*)(ws + 0);        // 1 MiB
    const uint_t* pm32       = (const uint_t*)(ws + 0);
    ushort_t* wqkvT = (ushort_t*)(ws + 1048576);
    ushort_t* woutT = (ushort_t*)(ws + 1343488);
    ushort_t* wff1T = (ushort_t*)(ws + 1441792);
    ushort_t* wff2T = (ushort_t*)(ws + 1835008);
    float*    pbsum = (float*)(ws + 2228224);                        // 16 KiB pooled sums
    float*    hbuf  = (float*)(ws + 4194304);                        // 8 MiB fp32 residual
    ushort_t* hb16  = (ushort_t*)(ws + 12582912);                    // 4 MiB bf16 mirror
    ushort_t* a16   = (ushort_t*)(ws + 41943040);                    // 4 MiB attn out

    preproc_kernel<<<PM_BLK + RQ_BLK + TW_BLK + T1_BLK + T2_BLK + PB_BLK + EM_BLK, 256, 0, stream>>>(
        mask, pm64, Wq, Wk, Wv, wqkvT, Wout, woutT, Wff1, wff1T, Wff2, wff2T,
        pbsum, x, We, hbuf, hb16);

    for (int l = 0; l < L_LAYERS; l++) {
        qkv_attn_kernel<<<512, 512, 0, stream>>>(
            hb16, wqkvT + (size_t)l * 384 * 128, pm32, a16);
        tail_kernel<<<M_ROWS / 32, 256, 0, stream>>>(
            a16, woutT + (size_t)l * 128 * 128, wff1T + (size_t)l * 512 * 128,
            wff2T + (size_t)l * 128 * 512, bff1 + l * 512, bff2 + l * 128,
            hbuf, hb16, pbsum, (l == L_LAYERS - 1) ? 1 : 0);
    }

    readout_kernel<<<512, 256, 0, stream>>>(hbuf, pbsum, Wp, Wr, br, out);
}

// Round 15
// 276.973 us; speedup vs baseline: 1.1579x; 1.0135x over previous
//
#include <hip/hip_runtime.h>
#include <cstdint>
#include <cstddef>

#define L_LAYERS 3
#define H_HEADS 8
#define D_EMB 128
#define DKV 16
#define FF_DIM 512
#define B_BATCH 32
#define N_SEQ 512
#define F_INP 16
#define OUT_DIM 3
#define M_ROWS (B_BATCH * N_SEQ)   // 16384
#define QSCALE 0.3606737602222409f // 0.25 * log2(e): scores in log2 domain

typedef unsigned short ushort_t;
typedef unsigned int uint_t;
typedef __attribute__((ext_vector_type(8))) short short8;
typedef __attribute__((ext_vector_type(4))) float f32x4;
typedef __attribute__((ext_vector_type(16))) float f32x16;

__device__ inline ushort_t f2bf(float x) {   // RNE float->bf16
    union { float f; uint_t u; } v; v.f = x;
    uint_t r = v.u + 0x7fffu + ((v.u >> 16) & 1u);
    return (ushort_t)(r >> 16);
}

__device__ inline uint_t pack2bf_tr(float a, float b) {  // truncating pack: lo=a, hi=b
    union { float f; uint_t u; } ua, ub;
    ua.f = a; ub.f = b;
    return (ua.u >> 16) | (ub.u & 0xffff0000u);
}

__device__ inline float exp2fast(float x) {   // raw v_exp_f32 (2^x)
#if __has_builtin(__builtin_amdgcn_exp2f)
    return __builtin_amdgcn_exp2f(x);
#else
    float r; __asm__("v_exp_f32 %0, %1" : "=v"(r) : "v"(x)); return r;
#endif
}

__device__ inline void gload16(const void* g, void* l) {
    __builtin_amdgcn_global_load_lds(
        (const __attribute__((address_space(1))) unsigned int*)g,
        (__attribute__((address_space(3))) unsigned int*)l, 16, 0, 0);
}

// ---------------- fused preprocessing (+ pbsum zeroing) ----------------
#define PM_BLK 32768
#define RQ_BLK 576
#define TW_BLK 192
#define T1_BLK 768
#define T2_BLK 768
#define PB_BLK 16
#define EM_BLK 8192
__global__ __launch_bounds__(256) void preproc_kernel(
        const int* __restrict__ mask, unsigned long long* __restrict__ pm,
        const float* __restrict__ Wq, const float* __restrict__ Wk,
        const float* __restrict__ Wv, ushort_t* __restrict__ wqkvT,
        const float* __restrict__ Wout, ushort_t* __restrict__ woutT,
        const float* __restrict__ Wff1, ushort_t* __restrict__ wff1T,
        const float* __restrict__ Wff2, ushort_t* __restrict__ wff2T,
        float* __restrict__ pbsum,
        const float* __restrict__ x, const float* __restrict__ We,
        float* __restrict__ hf, ushort_t* __restrict__ hb) {
    int bx = blockIdx.x;
    const int tid = threadIdx.x;
    if (bx < PM_BLK) {
        int gid = bx * 256 + tid;
        int v = mask[gid];
        unsigned long long bal = __ballot(v != 0);
        if ((tid & 63) == 0) pm[gid >> 6] = bal;
        return;
    }
    bx -= PM_BLK;
    if (bx < RQ_BLK) {
        int idx = bx * 256 + tid;
        int d = idx & 127;
        int n = (idx >> 7) % 384;
        int l = idx / (384 * 128);
        int proj = n >> 7, hh = (n & 127) >> 4, kk = n & 15;
        const float* src = proj == 0 ? Wq : proj == 1 ? Wk : Wv;
        wqkvT[idx] = f2bf(src[((size_t)(l * 8 + hh) * 128 + d) * 16 + kk]);
        return;
    }
    bx -= RQ_BLK;
    if (bx < TW_BLK + T1_BLK + T2_BLK) {
        const float* src; ushort_t* dst; int R, C;
        if (bx < TW_BLK) { src = Wout; dst = woutT; R = 128; C = 128; }
        else if (bx < TW_BLK + T1_BLK) { src = Wff1; dst = wff1T; R = 128; C = 512; bx -= TW_BLK; }
        else { src = Wff2; dst = wff2T; R = 512; C = 128; bx -= TW_BLK + T1_BLK; }
        int idx = bx * 256 + tid;
        int b = idx / (R * C);
        int rem = idx - b * (R * C);
        int r = rem / C, c = rem - r * C;
        dst[(size_t)b * R * C + (size_t)c * R + r] = f2bf(src[idx]);
        return;
    }
    bx -= TW_BLK + T1_BLK + T2_BLK;
    if (bx < PB_BLK) {
        pbsum[bx * 256 + tid] = 0.f;
        return;
    }
    bx -= PB_BLK;
    {
        const int d = tid & 127;
        const int m = bx * 2 + (tid >> 7);
        const float* xr = x + (size_t)m * 16;
        float acc = 0.f;
#pragma unroll
        for (int k = 0; k < 16; k++) acc += xr[k] * We[k * 128 + d];
        acc = fmaxf(acc, 0.f);
        hf[(size_t)m * 128 + d] = acc;
        hb[(size_t)m * 128 + d] = f2bf(acc);
    }
}

// ---------------- fused QKV-GEMM + flash attention v5: single-pass (zero-shift exp2) ----------------
// Block = (b,h,half): 512 blocks x 512 thr (8 waves). LDS 53.5 KB.
// Scores in log2 domain (Q prescaled by 0.25*log2e); p = 2^s directly — no max pass
// (softmax is shift-invariant; |s| << 126 so no overflow/underflow; fp is scale-invariant).
// lsum via ones-MFMA in C-layout matching oacc -> pure in-lane normalize.
__global__ __launch_bounds__(512, 2) void qkv_attn_kernel(
        const ushort_t* __restrict__ hb,    // [16384][128] bf16
        const ushort_t* __restrict__ WqkvT, // layer slice [384][128] bf16 B^T
        const uint_t* __restrict__ pm,      // packed mask
        ushort_t* __restrict__ Aout) {      // [16384][128] bf16
    __shared__ __align__(16) ushort_t sm[26752];   // 53.5 KB
    ushort_t* KF = sm;            // 16 tiles * 512        [0, 8192)
    ushort_t* Vt = sm + 8192;     // [16][520]             [8192, 16512)
    ushort_t* Qs = sm + 16512;    // [256][16]             [16512, 20608)  phase 1+qf
    ushort_t* Ws = sm + 20608;    // [48][128]             [20608, 26752)  phase 1 only
    ushort_t* Ps = sm + 16512;    // 8 x 32x36 = 9216      [16512, 25728)  phase 2, aliases Qs+Ws

    const int tid = threadIdx.x;
    const int w = tid >> 6, L = tid & 63;
    const int lr = L & 15, lq = L >> 4;
    const int lane31 = L & 31, lhalf = L >> 5;
    const int bx = blockIdx.x;
    const int b = bx >> 4, h = (bx >> 1) & 7, half = bx & 1;

    // ---- stage W slice [48 rows n][128 k]: n<16:Q, 16..31:K, 32..47:V ----
    for (int i = tid; i < 768; i += 512) {
        const int row = i >> 4, cg = i & 15;
        const int proj = row >> 4, kk = row & 15;
        gload16(WqkvT + (size_t)(proj * 128 + h * 16 + kk) * 128 + cg * 8, &Ws[i * 8]);
    }
    __syncthreads();

    // ---- QKV GEMM: A-frags direct from global (L2-hot hb), Ws from LDS ----
    const ushort_t* Ab = hb + (size_t)b * 512 * 128;
    for (int mc = 0; mc < 4; mc++) {
        f32x4 acc[3];
#pragma unroll
        for (int j = 0; j < 3; j++) acc[j] = (f32x4){0.f, 0.f, 0.f, 0.f};
#pragma unroll
        for (int k0 = 0; k0 < 128; k0 += 32) {
            short8 af = *(const short8*)(Ab + (size_t)(mc * 128 + w * 16 + lr) * 128 + k0 + lq * 8);
#pragma unroll
            for (int j = 0; j < 3; j++) {
                short8 bf = *(const short8*)&Ws[(j * 16 + lr) * 128 + k0 + lq * 8];
                acc[j] = __builtin_amdgcn_mfma_f32_16x16x32_bf16(af, bf, acc[j], 0, 0, 0);
            }
        }
        // epilogue: C layout col = j*16+lr, row = lq*4+r
        const int rbase = mc * 128 + w * 16 + lq * 4;
#pragma unroll
        for (int r = 0; r < 4; r++) {
            const int key = rbase + r;
            KF[(key >> 5) * 512 + ((lr >> 3) * 32 + (key & 31)) * 8 + (lr & 7)] = f2bf(acc[1][r]);
            Vt[lr * 520 + key] = f2bf(acc[2][r]);
        }
        if ((mc >> 1) == half) {
            const int qb = (mc & 1) * 128 + w * 16 + lq * 4;
#pragma unroll
            for (int r = 0; r < 4; r++)
                Qs[(qb + r) * 16 + lr] = f2bf(acc[0][r] * QSCALE);
        }
    }
    __syncthreads();

    // ---- read Q frag + mask, then free Qs for Ps aliasing ----
    const int q0g = half * 256 + w * 32;
    const short8 qf = *(const short8*)&Qs[(w * 32 + lane31) * 16 + lhalf * 8];
    const uint_t* pmr = pm + (size_t)(b * 512 + q0g + lane31) * 16;
    const uint4 mwa = *(const uint4*)(pmr);
    const uint4 mwb = *(const uint4*)(pmr + 4);
    const uint4 mwc = *(const uint4*)(pmr + 8);
    const uint4 mwd = *(const uint4*)(pmr + 12);
    const uint_t mw[16] = {mwa.x, mwa.y, mwa.z, mwa.w, mwb.x, mwb.y, mwb.z, mwb.w,
                           mwc.x, mwc.y, mwc.z, mwc.w, mwd.x, mwd.y, mwd.z, mwd.w};
    __syncthreads();   // all qf reads done; Qs region now writable as Ps

    const f32x16 zero16 = (f32x16)(0.f);
    short8 vone;
#pragma unroll
    for (int i = 0; i < 8; i++) vone[i] = (short)0x3F80;   // bf16 1.0

    // ---- single pass: QK -> 2^s (no shift) -> mask-zero -> pack -> PV + lsum-MFMA ----
    f32x4 oacc0 = (f32x4){0.f, 0.f, 0.f, 0.f};
    f32x4 oacc1 = (f32x4){0.f, 0.f, 0.f, 0.f};
    f32x4 lacc0 = (f32x4){0.f, 0.f, 0.f, 0.f};
    f32x4 lacc1 = (f32x4){0.f, 0.f, 0.f, 0.f};
#pragma unroll
    for (int t = 0; t < 16; t++) {
        short8 kf = *(const short8*)&KF[t * 512 + L * 8];
        f32x16 s = __builtin_amdgcn_mfma_f32_32x32x16_bf16(kf, qf, zero16, 0, 0, 0);
        const uint_t word = mw[t];
#pragma unroll
        for (int r = 0; r < 16; r++) {
            const int keyl = (r & 3) + 8 * (r >> 2) + 4 * lhalf;
            const float e = exp2fast(s[r]);
            s[r] = (word & (1u << keyl)) ? e : 0.f;
        }
#pragma unroll
        for (int g = 0; g < 4; g++) {
            const uint_t lo = pack2bf_tr(s[g * 4 + 0], s[g * 4 + 1]);
            const uint_t hi = pack2bf_tr(s[g * 4 + 2], s[g * 4 + 3]);
            *(uint2*)&Ps[w * 1152 + lane31 * 36 + g * 8 + 4 * lhalf] = make_uint2(lo, hi);
        }
        short8 vb = *(const short8*)&Vt[lr * 520 + t * 32 + lq * 8];
        short8 pa0 = *(const short8*)&Ps[w * 1152 + lr * 36 + lq * 8];
        short8 pa1 = *(const short8*)&Ps[w * 1152 + (16 + lr) * 36 + lq * 8];
        oacc0 = __builtin_amdgcn_mfma_f32_16x16x32_bf16(pa0, vb, oacc0, 0, 0, 0);
        oacc1 = __builtin_amdgcn_mfma_f32_16x16x32_bf16(pa1, vb, oacc1, 0, 0, 0);
        lacc0 = __builtin_amdgcn_mfma_f32_16x16x32_bf16(pa0, vone, lacc0, 0, 0, 0);
        lacc1 = __builtin_amdgcn_mfma_f32_16x16x32_bf16(pa1, vone, lacc1, 0, 0, 0);
    }

    // ---- normalize in-lane (lacc lane-mapping matches oacc exactly) ----
#pragma unroll
    for (int qa = 0; qa < 2; qa++) {
        const f32x4 oa = qa ? oacc1 : oacc0;
        const f32x4 la = qa ? lacc1 : lacc0;
#pragma unroll
        for (int rr = 0; rr < 4; rr++) {
            const int qloc = qa * 16 + lq * 4 + rr;
            Aout[(size_t)(b * 512 + q0g + qloc) * 128 + h * 16 + lr] = f2bf(oa[rr] / la[rr]);
        }
    }
}

// ---------------- fused layer tail (R11 staged version — measured best) ----------------
__global__ __launch_bounds__(256, 2) void tail_kernel(
        const ushort_t* __restrict__ A,     // a16 [16384][128]
        const ushort_t* __restrict__ WoT,   // [128 n][128 k]
        const ushort_t* __restrict__ W1T,   // [512 n][128 k]
        const ushort_t* __restrict__ W2T,   // [128 n][512 k]
        const float* __restrict__ b1,
        const float* __restrict__ b2,
        float* __restrict__ hf, ushort_t* __restrict__ hb,
        float* __restrict__ pbsum, int accum) {
    __shared__ __align__(16) ushort_t sm[38400];          // 76.8 KB -> 2 blocks/CU
    ushort_t* As  = sm;
    ushort_t* Bs  = sm + 1024;
    ushort_t* C1b = sm + 17408;
    ushort_t* T   = sm + 21760;

    const int tid = threadIdx.x;
    const int w = tid >> 6, l = tid & 63;
    const int lr = l & 15, lq = l >> 4;
    const int srow = (l >> 2);
    const int scol = (l & 3) * 8;
    const int m0 = blockIdx.x * 32;

    // phase A: C1 = a16 @ WoT^T + h
    f32x4 c1a[2][2];
#pragma unroll
    for (int i = 0; i < 2; i++)
#pragma unroll
        for (int j = 0; j < 2; j++) c1a[i][j] = (f32x4){0.f, 0.f, 0.f, 0.f};
    for (int k0 = 0; k0 < 128; k0 += 32) {
        if (w < 2)
            gload16(A + (size_t)(m0 + w * 16 + srow) * 128 + k0 + scol,
                    &As[(w * 16 + srow) * 32 + scol]);
#pragma unroll
        for (int it = 0; it < 2; it++)
            gload16(WoT + (size_t)(it * 64 + w * 16 + srow) * 128 + k0 + scol,
                    &Bs[(it * 64 + w * 16 + srow) * 32 + scol]);
        __syncthreads();
        short8 af[2], bfr[2];
#pragma unroll
        for (int i = 0; i < 2; i++) af[i] = *(const short8*)&As[(i * 16 + lr) * 32 + lq * 8];
#pragma unroll
        for (int j = 0; j < 2; j++) bfr[j] = *(const short8*)&Bs[(w * 32 + j * 16 + lr) * 32 + lq * 8];
#pragma unroll
        for (int i = 0; i < 2; i++)
#pragma unroll
            for (int j = 0; j < 2; j++)
                c1a[i][j] = __builtin_amdgcn_mfma_f32_16x16x32_bf16(af[i], bfr[j], c1a[i][j], 0, 0, 0);
        __syncthreads();
    }
    float c1[2][2][4];
#pragma unroll
    for (int i = 0; i < 2; i++)
#pragma unroll
        for (int r = 0; r < 4; r++) {
            const int row = i * 16 + lq * 4 + r;
#pragma unroll
            for (int j = 0; j < 2; j++) {
                const int n = w * 32 + j * 16 + lr;
                const float v = c1a[i][j][r] + hf[(size_t)(m0 + row) * 128 + n];
                c1[i][j][r] = v;
                C1b[row * 136 + n] = f2bf(v);
            }
        }
    __syncthreads();

    // phase B: T = relu(C1 @ W1T^T + b1)
    f32x4 ta[2][8];
#pragma unroll
    for (int i = 0; i < 2; i++)
#pragma unroll
        for (int j = 0; j < 8; j++) ta[i][j] = (f32x4){0.f, 0.f, 0.f, 0.f};
    for (int k0 = 0; k0 < 128; k0 += 32) {
#pragma unroll
        for (int it = 0; it < 8; it++)
            gload16(W1T + (size_t)(it * 64 + w * 16 + srow) * 128 + k0 + scol,
                    &Bs[(it * 64 + w * 16 + srow) * 32 + scol]);
        __syncthreads();
        short8 af[2], bfr[8];
#pragma unroll
        for (int i = 0; i < 2; i++) af[i] = *(const short8*)&C1b[(i * 16 + lr) * 136 + k0 + lq * 8];
#pragma unroll
        for (int j = 0; j < 8; j++) bfr[j] = *(const short8*)&Bs[(w * 128 + j * 16 + lr) * 32 + lq * 8];
#pragma unroll
        for (int i = 0; i < 2; i++)
#pragma unroll
            for (int j = 0; j < 8; j++)
                ta[i][j] = __builtin_amdgcn_mfma_f32_16x16x32_bf16(af[i], bfr[j], ta[i][j], 0, 0, 0);
        __syncthreads();
    }
#pragma unroll
    for (int j = 0; j < 8; j++) {
        const int n = w * 128 + j * 16 + lr;
        const float bv = b1[n];
#pragma unroll
        for (int i = 0; i < 2; i++)
#pragma unroll
            for (int r = 0; r < 4; r++) {
                const int row = i * 16 + lq * 4 + r;
                T[row * 520 + n] = f2bf(fmaxf(ta[i][j][r] + bv, 0.f));
            }
    }
    __syncthreads();

    // phase C: h' = C1 + T @ W2T^T + b2
    f32x4 oa[2][2];
#pragma unroll
    for (int i = 0; i < 2; i++)
#pragma unroll
        for (int j = 0; j < 2; j++) oa[i][j] = (f32x4){0.f, 0.f, 0.f, 0.f};
    for (int k0 = 0; k0 < 512; k0 += 32) {
#pragma unroll
        for (int it = 0; it < 2; it++)
            gload16(W2T + (size_t)(it * 64 + w * 16 + srow) * 512 + k0 + scol,
                    &Bs[(it * 64 + w * 16 + srow) * 32 + scol]);
        __syncthreads();
        short8 af[2], bfr[2];
#pragma unroll
        for (int i = 0; i < 2; i++) af[i] = *(const short8*)&T[(i * 16 + lr) * 520 + k0 + lq * 8];
#pragma unroll
        for (int j = 0; j < 2; j++) bfr[j] = *(const short8*)&Bs[(w * 32 + j * 16 + lr) * 32 + lq * 8];
#pragma unroll
        for (int i = 0; i < 2; i++)
#pragma unroll
            for (int j = 0; j < 2; j++)
                oa[i][j] = __builtin_amdgcn_mfma_f32_16x16x32_bf16(af[i], bfr[j], oa[i][j], 0, 0, 0);
        __syncthreads();
    }
#pragma unroll
    for (int j = 0; j < 2; j++) {
        const int n = w * 32 + j * 16 + lr;
        const float bv = b2[n];
        float psum = 0.f;
#pragma unroll
        for (int i = 0; i < 2; i++)
#pragma unroll
            for (int r = 0; r < 4; r++) {
                const int row = i * 16 + lq * 4 + r;
                const float v = oa[i][j][r] + bv + c1[i][j][r];
                psum += v;
                hf[(size_t)(m0 + row) * 128 + n] = v;
                hb[(size_t)(m0 + row) * 128 + n] = f2bf(v);
            }
        if (accum) {
            psum += __shfl_xor(psum, 16);
            psum += __shfl_xor(psum, 32);
            if (lq == 0) atomicAdd(&pbsum[(m0 >> 9) * 128 + n], psum);
        }
    }
}

// ------------- readout: 512 blocks, 32 rows each (unchanged) -------------
__global__ __launch_bounds__(256) void readout_kernel(const float* __restrict__ h,
                                                      const float* __restrict__ pbsum,
                                                      const float* __restrict__ Wp,
                                                      const float* __restrict__ Wr,
                                                      const float* __restrict__ br,
                                                      float* __restrict__ out) {
    const int u = blockIdx.x;
    const int b = u >> 4;
    const int m0 = u * 32;
    const int t = threadIdx.x;
    __shared__ float pooled[128];
    __shared__ float rp[128];
    __shared__ float pb3[3];
    if (t < 128) pooled[t] = pbsum[b * 128 + t] * (1.0f / 512.0f);
    __syncthreads();
    if (t < 128) {
        float a = 0.f;
        for (int dd = 0; dd < 128; dd++) a += pooled[dd] * Wp[dd * 128 + t];
        rp[t] = fmaxf(a, 0.f);
    }
    __syncthreads();
    if (t < OUT_DIM) {
        float a = br[t];
        for (int j = 0; j < 128; j++) a += rp[j] * Wr[j * 3 + t];
        pb3[t] = a;
    }
    __syncthreads();
    const int j = t & 7;
    const int row = m0 + (t >> 3);
    const float* hr = h + (size_t)row * 128 + j * 16;
    float a0 = 0.f, a1 = 0.f, a2o = 0.f;
#pragma unroll
    for (int dd = 0; dd < 16; dd++) {
        const float v = fmaxf(hr[dd], 0.f);
        const float* wr = Wr + (size_t)(128 + j * 16 + dd) * 3;
        a0 += v * wr[0]; a1 += v * wr[1]; a2o += v * wr[2];
    }
#pragma unroll
    for (int off = 4; off; off >>= 1) {
        a0 += __shfl_down(a0, off, 8);
        a1 += __shfl_down(a1, off, 8);
        a2o += __shfl_down(a2o, off, 8);
    }
    if (j == 0) {
        out[(size_t)row * 3 + 0] = a0 + pb3[0];
        out[(size_t)row * 3 + 1] = a1 + pb3[1];
        out[(size_t)row * 3 + 2] = a2o + pb3[2];
    }
}

extern "C" void kernel_launch(void* const* d_in, const int* in_sizes, int n_in,
                              void* d_out, int out_size, void* d_ws, size_t ws_size,
                              hipStream_t stream) {
    const float* x    = (const float*)d_in[0];
    const int*   mask = (const int*)d_in[1];
    const float* We   = (const float*)d_in[2];
    const float* Wq   = (const float*)d_in[3];
    const float* Wk   = (const float*)d_in[4];
    const float* Wv   = (const float*)d_in[5];
    const float* Wout = (const float*)d_in[6];
    const float* Wff1 = (const float*)d_in[7];
    const float* bff1 = (const float*)d_in[8];
    const float* Wff2 = (const float*)d_in[9];
    const float* bff2 = (const float*)d_in[10];
    const float* Wp   = (const float*)d_in[11];
    const float* Wr   = (const float*)d_in[12];
    const float* br   = (const float*)d_in[13];
    float* out = (float*)d_out;

    char* ws = (char*)d_ws;
    unsigned long long* pm64 = (unsigned long long*)(ws + 0);        // 1 MiB
    const uint_t* pm32       = (const uint_t*)(ws + 0);
    ushort_t* wqkvT = (ushort_t*)(ws + 1048576);
    ushort_t* woutT = (ushort_t*)(ws + 1343488);
    ushort_t* wff1T = (ushort_t*)(ws + 1441792);
    ushort_t* wff2T = (ushort_t*)(ws + 1835008);
    float*    pbsum = (float*)(ws + 2228224);                        // 16 KiB pooled sums
    float*    hbuf  = (float*)(ws + 4194304);                        // 8 MiB fp32 residual
    ushort_t* hb16  = (ushort_t*)(ws + 12582912);                    // 4 MiB bf16 mirror
    ushort_t* a16   = (ushort_t*)(ws + 41943040);                    // 4 MiB attn out

    preproc_kernel<<<PM_BLK + RQ_BLK + TW_BLK + T1_BLK + T2_BLK + PB_BLK + EM_BLK, 256, 0, stream>>>(
        mask, pm64, Wq, Wk, Wv, wqkvT, Wout, woutT, Wff1, wff1T, Wff2, wff2T,
        pbsum, x, We, hbuf, hb16);

    for (int l = 0; l < L_LAYERS; l++) {
        qkv_attn_kernel<<<512, 512, 0, stream>>>(
            hb16, wqkvT + (size_t)l * 384 * 128, pm32, a16);
        tail_kernel<<<M_ROWS / 32, 256, 0, stream>>>(
            a16, woutT + (size_t)l * 128 * 128, wff1T + (size_t)l * 512 * 128,
            wff2T + (size_t)l * 128 * 512, bff1 + l * 512, bff2 + l * 128,
            hbuf, hb16, pbsum, (l == L_LAYERS - 1) ? 1 : 0);
    }

    readout_kernel<<<512, 256, 0, stream>>>(hbuf, pbsum, Wp, Wr, br, out);
}

// Round 16
// 268.701 us; speedup vs baseline: 1.1936x; 1.0308x over previous
//
#include <hip/hip_runtime.h>
#include <cstdint>
#include <cstddef>

#define L_LAYERS 3
#define H_HEADS 8
#define D_EMB 128
#define DKV 16
#define FF_DIM 512
#define B_BATCH 32
#define N_SEQ 512
#define F_INP 16
#define OUT_DIM 3
#define M_ROWS (B_BATCH * N_SEQ)   // 16384
#define QSCALE 0.3606737602222409f // 0.25 * log2(e): scores in log2 domain

typedef unsigned short ushort_t;
typedef unsigned int uint_t;
typedef __attribute__((ext_vector_type(8))) short short8;
typedef __attribute__((ext_vector_type(4))) float f32x4;
typedef __attribute__((ext_vector_type(16))) float f32x16;

__device__ inline ushort_t f2bf(float x) {   // RNE float->bf16
    union { float f; uint_t u; } v; v.f = x;
    uint_t r = v.u + 0x7fffu + ((v.u >> 16) & 1u);
    return (ushort_t)(r >> 16);
}

__device__ inline uint_t pack2bf_tr(float a, float b) {  // truncating pack: lo=a, hi=b
    union { float f; uint_t u; } ua, ub;
    ua.f = a; ub.f = b;
    return (ua.u >> 16) | (ub.u & 0xffff0000u);
}

__device__ inline float exp2fast(float x) {   // raw v_exp_f32 (2^x)
#if __has_builtin(__builtin_amdgcn_exp2f)
    return __builtin_amdgcn_exp2f(x);
#else
    float r; __asm__("v_exp_f32 %0, %1" : "=v"(r) : "v"(x)); return r;
#endif
}

__device__ inline void gload16(const void* g, void* l) {
    __builtin_amdgcn_global_load_lds(
        (const __attribute__((address_space(1))) unsigned int*)g,
        (__attribute__((address_space(3))) unsigned int*)l, 16, 0, 0);
}

// ---------------- fused preprocessing (+ pbsum zeroing) ----------------
#define PM_BLK 32768
#define RQ_BLK 576
#define TW_BLK 192
#define T1_BLK 768
#define T2_BLK 768
#define PB_BLK 16
#define EM_BLK 8192
__global__ __launch_bounds__(256) void preproc_kernel(
        const int* __restrict__ mask, unsigned long long* __restrict__ pm,
        const float* __restrict__ Wq, const float* __restrict__ Wk,
        const float* __restrict__ Wv, ushort_t* __restrict__ wqkvT,
        const float* __restrict__ Wout, ushort_t* __restrict__ woutT,
        const float* __restrict__ Wff1, ushort_t* __restrict__ wff1T,
        const float* __restrict__ Wff2, ushort_t* __restrict__ wff2T,
        float* __restrict__ pbsum,
        const float* __restrict__ x, const float* __restrict__ We,
        float* __restrict__ hf, ushort_t* __restrict__ hb) {
    int bx = blockIdx.x;
    const int tid = threadIdx.x;
    if (bx < PM_BLK) {
        int gid = bx * 256 + tid;
        int v = mask[gid];
        unsigned long long bal = __ballot(v != 0);
        if ((tid & 63) == 0) pm[gid >> 6] = bal;
        return;
    }
    bx -= PM_BLK;
    if (bx < RQ_BLK) {
        int idx = bx * 256 + tid;
        int d = idx & 127;
        int n = (idx >> 7) % 384;
        int l = idx / (384 * 128);
        int proj = n >> 7, hh = (n & 127) >> 4, kk = n & 15;
        const float* src = proj == 0 ? Wq : proj == 1 ? Wk : Wv;
        wqkvT[idx] = f2bf(src[((size_t)(l * 8 + hh) * 128 + d) * 16 + kk]);
        return;
    }
    bx -= RQ_BLK;
    if (bx < TW_BLK + T1_BLK + T2_BLK) {
        const float* src; ushort_t* dst; int R, C;
        if (bx < TW_BLK) { src = Wout; dst = woutT; R = 128; C = 128; }
        else if (bx < TW_BLK + T1_BLK) { src = Wff1; dst = wff1T; R = 128; C = 512; bx -= TW_BLK; }
        else { src = Wff2; dst = wff2T; R = 512; C = 128; bx -= TW_BLK + T1_BLK; }
        int idx = bx * 256 + tid;
        int b = idx / (R * C);
        int rem = idx - b * (R * C);
        int r = rem / C, c = rem - r * C;
        dst[(size_t)b * R * C + (size_t)c * R + r] = f2bf(src[idx]);
        return;
    }
    bx -= TW_BLK + T1_BLK + T2_BLK;
    if (bx < PB_BLK) {
        pbsum[bx * 256 + tid] = 0.f;
        return;
    }
    bx -= PB_BLK;
    {
        const int d = tid & 127;
        const int m = bx * 2 + (tid >> 7);
        const float* xr = x + (size_t)m * 16;
        float acc = 0.f;
#pragma unroll
        for (int k = 0; k < 16; k++) acc += xr[k] * We[k * 128 + d];
        acc = fmaxf(acc, 0.f);
        hf[(size_t)m * 128 + d] = acc;
        hb[(size_t)m * 128 + d] = f2bf(acc);
    }
}

// ---------------- fused QKV-GEMM + flash attention v5 (R15 frozen, measured-best) ----------------
__global__ __launch_bounds__(512, 2) void qkv_attn_kernel(
        const ushort_t* __restrict__ hb,    // [16384][128] bf16
        const ushort_t* __restrict__ WqkvT, // layer slice [384][128] bf16 B^T
        const uint_t* __restrict__ pm,      // packed mask
        ushort_t* __restrict__ Aout) {      // [16384][128] bf16
    __shared__ __align__(16) ushort_t sm[26752];   // 53.5 KB
    ushort_t* KF = sm;            // 16 tiles * 512
    ushort_t* Vt = sm + 8192;     // [16][520]
    ushort_t* Qs = sm + 16512;    // [256][16]
    ushort_t* Ws = sm + 20608;    // [48][128]   (phase 1)
    ushort_t* Ps = sm + 16512;    // 8 x 32x36   (phase 2, aliases Qs+Ws)

    const int tid = threadIdx.x;
    const int w = tid >> 6, L = tid & 63;
    const int lr = L & 15, lq = L >> 4;
    const int lane31 = L & 31, lhalf = L >> 5;
    const int bx = blockIdx.x;
    const int b = bx >> 4, h = (bx >> 1) & 7, half = bx & 1;

    for (int i = tid; i < 768; i += 512) {
        const int row = i >> 4, cg = i & 15;
        const int proj = row >> 4, kk = row & 15;
        gload16(WqkvT + (size_t)(proj * 128 + h * 16 + kk) * 128 + cg * 8, &Ws[i * 8]);
    }
    __syncthreads();

    const ushort_t* Ab = hb + (size_t)b * 512 * 128;
    for (int mc = 0; mc < 4; mc++) {
        f32x4 acc[3];
#pragma unroll
        for (int j = 0; j < 3; j++) acc[j] = (f32x4){0.f, 0.f, 0.f, 0.f};
#pragma unroll
        for (int k0 = 0; k0 < 128; k0 += 32) {
            short8 af = *(const short8*)(Ab + (size_t)(mc * 128 + w * 16 + lr) * 128 + k0 + lq * 8);
#pragma unroll
            for (int j = 0; j < 3; j++) {
                short8 bf = *(const short8*)&Ws[(j * 16 + lr) * 128 + k0 + lq * 8];
                acc[j] = __builtin_amdgcn_mfma_f32_16x16x32_bf16(af, bf, acc[j], 0, 0, 0);
            }
        }
        const int rbase = mc * 128 + w * 16 + lq * 4;
#pragma unroll
        for (int r = 0; r < 4; r++) {
            const int key = rbase + r;
            KF[(key >> 5) * 512 + ((lr >> 3) * 32 + (key & 31)) * 8 + (lr & 7)] = f2bf(acc[1][r]);
            Vt[lr * 520 + key] = f2bf(acc[2][r]);
        }
        if ((mc >> 1) == half) {
            const int qb = (mc & 1) * 128 + w * 16 + lq * 4;
#pragma unroll
            for (int r = 0; r < 4; r++)
                Qs[(qb + r) * 16 + lr] = f2bf(acc[0][r] * QSCALE);
        }
    }
    __syncthreads();

    const int q0g = half * 256 + w * 32;
    const short8 qf = *(const short8*)&Qs[(w * 32 + lane31) * 16 + lhalf * 8];
    const uint_t* pmr = pm + (size_t)(b * 512 + q0g + lane31) * 16;
    const uint4 mwa = *(const uint4*)(pmr);
    const uint4 mwb = *(const uint4*)(pmr + 4);
    const uint4 mwc = *(const uint4*)(pmr + 8);
    const uint4 mwd = *(const uint4*)(pmr + 12);
    const uint_t mw[16] = {mwa.x, mwa.y, mwa.z, mwa.w, mwb.x, mwb.y, mwb.z, mwb.w,
                           mwc.x, mwc.y, mwc.z, mwc.w, mwd.x, mwd.y, mwd.z, mwd.w};
    __syncthreads();   // qf reads done; Qs region now writable as Ps

    const f32x16 zero16 = (f32x16)(0.f);
    short8 vone;
#pragma unroll
    for (int i = 0; i < 8; i++) vone[i] = (short)0x3F80;   // bf16 1.0

    f32x4 oacc0 = (f32x4){0.f, 0.f, 0.f, 0.f};
    f32x4 oacc1 = (f32x4){0.f, 0.f, 0.f, 0.f};
    f32x4 lacc0 = (f32x4){0.f, 0.f, 0.f, 0.f};
    f32x4 lacc1 = (f32x4){0.f, 0.f, 0.f, 0.f};
#pragma unroll
    for (int t = 0; t < 16; t++) {
        short8 kf = *(const short8*)&KF[t * 512 + L * 8];
        f32x16 s = __builtin_amdgcn_mfma_f32_32x32x16_bf16(kf, qf, zero16, 0, 0, 0);
        const uint_t word = mw[t];
#pragma unroll
        for (int r = 0; r < 16; r++) {
            const int keyl = (r & 3) + 8 * (r >> 2) + 4 * lhalf;
            const float e = exp2fast(s[r]);
            s[r] = (word & (1u << keyl)) ? e : 0.f;
        }
#pragma unroll
        for (int g = 0; g < 4; g++) {
            const uint_t lo = pack2bf_tr(s[g * 4 + 0], s[g * 4 + 1]);
            const uint_t hi = pack2bf_tr(s[g * 4 + 2], s[g * 4 + 3]);
            *(uint2*)&Ps[w * 1152 + lane31 * 36 + g * 8 + 4 * lhalf] = make_uint2(lo, hi);
        }
        short8 vb = *(const short8*)&Vt[lr * 520 + t * 32 + lq * 8];
        short8 pa0 = *(const short8*)&Ps[w * 1152 + lr * 36 + lq * 8];
        short8 pa1 = *(const short8*)&Ps[w * 1152 + (16 + lr) * 36 + lq * 8];
        oacc0 = __builtin_amdgcn_mfma_f32_16x16x32_bf16(pa0, vb, oacc0, 0, 0, 0);
        oacc1 = __builtin_amdgcn_mfma_f32_16x16x32_bf16(pa1, vb, oacc1, 0, 0, 0);
        lacc0 = __builtin_amdgcn_mfma_f32_16x16x32_bf16(pa0, vone, lacc0, 0, 0, 0);
        lacc1 = __builtin_amdgcn_mfma_f32_16x16x32_bf16(pa1, vone, lacc1, 0, 0, 0);
    }

#pragma unroll
    for (int qa = 0; qa < 2; qa++) {
        const f32x4 oa = qa ? oacc1 : oacc0;
        const f32x4 la = qa ? lacc1 : lacc0;
#pragma unroll
        for (int rr = 0; rr < 4; rr++) {
            const int qloc = qa * 16 + lq * 4 + rr;
            Aout[(size_t)(b * 512 + q0g + qloc) * 128 + h * 16 + lr] = f2bf(oa[rr] / la[rr]);
        }
    }
}

// ---------------- fused layer tail v4: ping-pong double-buffered staging ----------------
// stage(i+1) issues into the other buffer DURING compute(i): the vmcnt drain at each
// barrier overlaps MFMA instead of exposing full L2 latency (phases A/B/C).
__global__ __launch_bounds__(256, 2) void tail_kernel(
        const ushort_t* __restrict__ A,     // a16 [16384][128]
        const ushort_t* __restrict__ WoT,   // [128 n][128 k]
        const ushort_t* __restrict__ W1T,   // [512 n][128 k]
        const ushort_t* __restrict__ W2T,   // [128 n][512 k]
        const float* __restrict__ b1,
        const float* __restrict__ b2,
        float* __restrict__ hf, ushort_t* __restrict__ hb,
        float* __restrict__ pbsum, int accum) {
    __shared__ __align__(16) ushort_t sm[39424];   // 78.85 KB -> 2 blocks/CU
    ushort_t* AsA = sm;            // 1024  (32x32 chunk)
    ushort_t* AsB = sm + 1024;     // 1024
    ushort_t* BsA = sm + 2048;     // 8192  (up to 256x32 chunk)
    ushort_t* BsB = sm + 10240;    // 8192
    ushort_t* C1b = sm + 18432;    // 4352  (32x136)
    ushort_t* T   = sm + 22784;    // 16640 (32x520)

    const int tid = threadIdx.x;
    const int w = tid >> 6, l = tid & 63;
    const int lr = l & 15, lq = l >> 4;
    const int srow = (l >> 2);
    const int scol = (l & 3) * 8;
    const int m0 = blockIdx.x * 32;

    // ================ phase A: C1 = a16 @ WoT^T + h ================
    f32x4 c1a[2][2];
#pragma unroll
    for (int i = 0; i < 2; i++)
#pragma unroll
        for (int j = 0; j < 2; j++) c1a[i][j] = (f32x4){0.f, 0.f, 0.f, 0.f};
    // prologue: stage k0=0
    if (w < 2)
        gload16(A + (size_t)(m0 + w * 16 + srow) * 128 + scol, &AsA[(w * 16 + srow) * 32 + scol]);
#pragma unroll
    for (int it = 0; it < 2; it++)
        gload16(WoT + (size_t)(it * 64 + w * 16 + srow) * 128 + scol, &BsA[(it * 64 + w * 16 + srow) * 32 + scol]);
#pragma unroll
    for (int k0 = 0; k0 < 128; k0 += 32) {
        ushort_t* Ac = (k0 & 32) ? AsB : AsA;
        ushort_t* Bc = (k0 & 32) ? BsB : BsA;
        ushort_t* An = (k0 & 32) ? AsA : AsB;
        ushort_t* Bn = (k0 & 32) ? BsA : BsB;
        __syncthreads();   // chunk k0 staged; prior reads of An/Bn done
        if (k0 + 32 < 128) {
            if (w < 2)
                gload16(A + (size_t)(m0 + w * 16 + srow) * 128 + k0 + 32 + scol,
                        &An[(w * 16 + srow) * 32 + scol]);
#pragma unroll
            for (int it = 0; it < 2; it++)
                gload16(WoT + (size_t)(it * 64 + w * 16 + srow) * 128 + k0 + 32 + scol,
                        &Bn[(it * 64 + w * 16 + srow) * 32 + scol]);
        }
        short8 af[2], bfr[2];
#pragma unroll
        for (int i = 0; i < 2; i++) af[i] = *(const short8*)&Ac[(i * 16 + lr) * 32 + lq * 8];
#pragma unroll
        for (int j = 0; j < 2; j++) bfr[j] = *(const short8*)&Bc[(w * 32 + j * 16 + lr) * 32 + lq * 8];
#pragma unroll
        for (int i = 0; i < 2; i++)
#pragma unroll
            for (int j = 0; j < 2; j++)
                c1a[i][j] = __builtin_amdgcn_mfma_f32_16x16x32_bf16(af[i], bfr[j], c1a[i][j], 0, 0, 0);
    }
    // epilogue A: + residual h (fp32 regs + bf16 LDS)
    float c1[2][2][4];
#pragma unroll
    for (int i = 0; i < 2; i++)
#pragma unroll
        for (int r = 0; r < 4; r++) {
            const int row = i * 16 + lq * 4 + r;
#pragma unroll
            for (int j = 0; j < 2; j++) {
                const int n = w * 32 + j * 16 + lr;
                const float v = c1a[i][j][r] + hf[(size_t)(m0 + row) * 128 + n];
                c1[i][j][r] = v;
                C1b[row * 136 + n] = f2bf(v);
            }
        }

    // ================ phase B: T = relu(C1 @ W1T^T + b1), 2 n-halves x 4 k-chunks ================
    // prologue: stage chunk c=0 (nc=0,k0=0) — BsA free (last A read was BsA at k0=64, all waves past sync(96))
#pragma unroll
    for (int it = 0; it < 4; it++)
        gload16(W1T + (size_t)(it * 64 + w * 16 + srow) * 128 + scol, &BsA[(it * 64 + w * 16 + srow) * 32 + scol]);
#pragma unroll
    for (int nc = 0; nc < 2; nc++) {
        f32x4 ta[2][4];
#pragma unroll
        for (int i = 0; i < 2; i++)
#pragma unroll
            for (int j = 0; j < 4; j++) ta[i][j] = (f32x4){0.f, 0.f, 0.f, 0.f};
#pragma unroll
        for (int k0i = 0; k0i < 4; k0i++) {
            const int c = nc * 4 + k0i;
            ushort_t* Bc = (c & 1) ? BsB : BsA;
            ushort_t* Bn = (c & 1) ? BsA : BsB;
            __syncthreads();   // chunk c staged; also orders C1b writes (first iter)
            if (c + 1 < 8) {
                const int nc2 = (c + 1) >> 2, k02 = ((c + 1) & 3) * 32;
#pragma unroll
                for (int it = 0; it < 4; it++)
                    gload16(W1T + (size_t)(nc2 * 256 + it * 64 + w * 16 + srow) * 128 + k02 + scol,
                            &Bn[(it * 64 + w * 16 + srow) * 32 + scol]);
            }
            short8 af[2], bfr[4];
#pragma unroll
            for (int i = 0; i < 2; i++)
                af[i] = *(const short8*)&C1b[(i * 16 + lr) * 136 + k0i * 32 + lq * 8];
#pragma unroll
            for (int j = 0; j < 4; j++)
                bfr[j] = *(const short8*)&Bc[(w * 64 + j * 16 + lr) * 32 + lq * 8];
#pragma unroll
            for (int i = 0; i < 2; i++)
#pragma unroll
                for (int j = 0; j < 4; j++)
                    ta[i][j] = __builtin_amdgcn_mfma_f32_16x16x32_bf16(af[i], bfr[j], ta[i][j], 0, 0, 0);
        }
        // epilogue nc: +b1, relu -> T (distinct region; staging for next chunk flies concurrently)
#pragma unroll
        for (int j = 0; j < 4; j++) {
            const int n = nc * 256 + w * 64 + j * 16 + lr;
            const float bv = b1[n];
#pragma unroll
            for (int i = 0; i < 2; i++)
#pragma unroll
                for (int r = 0; r < 4; r++) {
                    const int row = i * 16 + lq * 4 + r;
                    T[row * 520 + n] = f2bf(fmaxf(ta[i][j][r] + bv, 0.f));
                }
        }
    }

    // ================ phase C: h' = C1 + T @ W2T^T + b2, 16 k-chunks ================
    // prologue: stage k0=0 into BsA (last B read of BsA was c=6; all waves past sync(c=7))
#pragma unroll
    for (int it = 0; it < 2; it++)
        gload16(W2T + (size_t)(it * 64 + w * 16 + srow) * 512 + scol, &BsA[(it * 64 + w * 16 + srow) * 32 + scol]);
    f32x4 oa[2][2];
#pragma unroll
    for (int i = 0; i < 2; i++)
#pragma unroll
        for (int j = 0; j < 2; j++) oa[i][j] = (f32x4){0.f, 0.f, 0.f, 0.f};
#pragma unroll
    for (int k0 = 0; k0 < 512; k0 += 32) {
        ushort_t* Bc = ((k0 >> 5) & 1) ? BsB : BsA;
        ushort_t* Bn = ((k0 >> 5) & 1) ? BsA : BsB;
        __syncthreads();   // chunk staged; T writes ordered (first iter)
        if (k0 + 32 < 512) {
#pragma unroll
            for (int it = 0; it < 2; it++)
                gload16(W2T + (size_t)(it * 64 + w * 16 + srow) * 512 + k0 + 32 + scol,
                        &Bn[(it * 64 + w * 16 + srow) * 32 + scol]);
        }
        short8 af[2], bfr[2];
#pragma unroll
        for (int i = 0; i < 2; i++)
            af[i] = *(const short8*)&T[(i * 16 + lr) * 520 + k0 + lq * 8];
#pragma unroll
        for (int j = 0; j < 2; j++)
            bfr[j] = *(const short8*)&Bc[(w * 32 + j * 16 + lr) * 32 + lq * 8];
#pragma unroll
        for (int i = 0; i < 2; i++)
#pragma unroll
            for (int j = 0; j < 2; j++)
                oa[i][j] = __builtin_amdgcn_mfma_f32_16x16x32_bf16(af[i], bfr[j], oa[i][j], 0, 0, 0);
    }
    // epilogue C: + b2 + C1 -> global fp32 + bf16 (+ pooled-sum atomics on last layer)
#pragma unroll
    for (int j = 0; j < 2; j++) {
        const int n = w * 32 + j * 16 + lr;
        const float bv = b2[n];
        float psum = 0.f;
#pragma unroll
        for (int i = 0; i < 2; i++)
#pragma unroll
            for (int r = 0; r < 4; r++) {
                const int row = i * 16 + lq * 4 + r;
                const float v = oa[i][j][r] + bv + c1[i][j][r];
                psum += v;
                hf[(size_t)(m0 + row) * 128 + n] = v;
                hb[(size_t)(m0 + row) * 128 + n] = f2bf(v);
            }
        if (accum) {
            psum += __shfl_xor(psum, 16);
            psum += __shfl_xor(psum, 32);
            if (lq == 0) atomicAdd(&pbsum[(m0 >> 9) * 128 + n], psum);
        }
    }
}

// ------------- readout: 512 blocks, 32 rows each (unchanged) -------------
__global__ __launch_bounds__(256) void readout_kernel(const float* __restrict__ h,
                                                      const float* __restrict__ pbsum,
                                                      const float* __restrict__ Wp,
                                                      const float* __restrict__ Wr,
                                                      const float* __restrict__ br,
                                                      float* __restrict__ out) {
    const int u = blockIdx.x;
    const int b = u >> 4;
    const int m0 = u * 32;
    const int t = threadIdx.x;
    __shared__ float pooled[128];
    __shared__ float rp[128];
    __shared__ float pb3[3];
    if (t < 128) pooled[t] = pbsum[b * 128 + t] * (1.0f / 512.0f);
    __syncthreads();
    if (t < 128) {
        float a = 0.f;
        for (int dd = 0; dd < 128; dd++) a += pooled[dd] * Wp[dd * 128 + t];
        rp[t] = fmaxf(a, 0.f);
    }
    __syncthreads();
    if (t < OUT_DIM) {
        float a = br[t];
        for (int j = 0; j < 128; j++) a += rp[j] * Wr[j * 3 + t];
        pb3[t] = a;
    }
    __syncthreads();
    const int j = t & 7;
    const int row = m0 + (t >> 3);
    const float* hr = h + (size_t)row * 128 + j * 16;
    float a0 = 0.f, a1 = 0.f, a2o = 0.f;
#pragma unroll
    for (int dd = 0; dd < 16; dd++) {
        const float v = fmaxf(hr[dd], 0.f);
        const float* wr = Wr + (size_t)(128 + j * 16 + dd) * 3;
        a0 += v * wr[0]; a1 += v * wr[1]; a2o += v * wr[2];
    }
#pragma unroll
    for (int off = 4; off; off >>= 1) {
        a0 += __shfl_down(a0, off, 8);
        a1 += __shfl_down(a1, off, 8);
        a2o += __shfl_down(a2o, off, 8);
    }
    if (j == 0) {
        out[(size_t)row * 3 + 0] = a0 + pb3[0];
        out[(size_t)row * 3 + 1] = a1 + pb3[1];
        out[(size_t)row * 3 + 2] = a2o + pb3[2];
    }
}

extern "C" void kernel_launch(void* const* d_in, const int* in_sizes, int n_in,
                              void* d_out, int out_size, void* d_ws, size_t ws_size,
                              hipStream_t stream) {
    const float* x    = (const float*)d_in[0];
    const int*   mask = (const int*)d_in[1];
    const float* We   = (const float*)d_in[2];
    const float* Wq   = (const float*)d_in[3];
    const float* Wk   = (const float*)d_in[4];
    const float* Wv   = (const float*)d_in[5];
    const float* Wout = (const float*)d_in[6];
    const float* Wff1 = (const float*)d_in[7];
    const float* bff1 = (const float*)d_in[8];
    const float* Wff2 = (const float*)d_in[9];
    const float* bff2 = (const float*)d_in[10];
    const float* Wp   = (const float*)d_in[11];
    const float* Wr   = (const float*)d_in[12];
    const float* br   = (const float*)d_in[13];
    float* out = (float*)d_out;

    char* ws = (char*)d_ws;
    unsigned long long* pm64 = (unsigned long long*)(ws + 0);        // 1 MiB
    const uint_t* pm32       = (const uint_t*)(ws + 0);
    ushort_t* wqkvT = (ushort_t*)(ws + 1048576);
    ushort_t* woutT = (ushort_t*)(ws + 1343488);
    ushort_t* wff1T = (ushort_t*)(ws + 1441792);
    ushort_t* wff2T = (ushort_t*)(ws + 1835008);
    float*    pbsum = (float*)(ws + 2228224);                        // 16 KiB pooled sums
    float*    hbuf  = (float*)(ws + 4194304);                        // 8 MiB fp32 residual
    ushort_t* hb16  = (ushort_t*)(ws + 12582912);                    // 4 MiB bf16 mirror
    ushort_t* a16   = (ushort_t*)(ws + 41943040);                    // 4 MiB attn out

    preproc_kernel<<<PM_BLK + RQ_BLK + TW_BLK + T1_BLK + T2_BLK + PB_BLK + EM_BLK, 256, 0, stream>>>(
        mask, pm64, Wq, Wk, Wv, wqkvT, Wout, woutT, Wff1, wff1T, Wff2, wff2T,
        pbsum, x, We, hbuf, hb16);

    for (int l = 0; l < L_LAYERS; l++) {
        qkv_attn_kernel<<<512, 512, 0, stream>>>(
            hb16, wqkvT + (size_t)l * 384 * 128, pm32, a16);
        tail_kernel<<<M_ROWS / 32, 256, 0, stream>>>(
            a16, woutT + (size_t)l * 128 * 128, wff1T + (size_t)l * 512 * 128,
            wff2T + (size_t)l * 128 * 512, bff1 + l * 512, bff2 + l * 128,
            hbuf, hb16, pbsum, (l == L_LAYERS - 1) ? 1 : 0);
    }

    readout_kernel<<<512, 256, 0, stream>>>(hbuf, pbsum, Wp, Wr, br, out);
}